// Round 2
// 734.972 us; speedup vs baseline: 1.2027x; 1.2027x over previous
//
#include <hip/hip_runtime.h>

#define NN 100000
#define EE 1600000

typedef __attribute__((ext_vector_type(8))) __bf16 bf16x8;
typedef __attribute__((ext_vector_type(4))) float f32x4;
typedef unsigned short u16;

__device__ __forceinline__ float bf2f(u16 v) {
  union { unsigned u; float f; } x; x.u = ((unsigned)v) << 16; return x.f;
}
__device__ __forceinline__ u16 f2bf(float f) {
  union { unsigned u; float f; } x; x.f = f;
  x.u += 0x7fffu + ((x.u >> 16) & 1u);
  return (u16)(x.u >> 16);
}
__device__ __forceinline__ float lo_f(unsigned u) {
  union { unsigned u; float f; } x; x.u = u << 16; return x.f;
}
__device__ __forceinline__ float hi_f(unsigned u) {
  union { unsigned u; float f; } x; x.u = u & 0xffff0000u; return x.f;
}
__device__ __forceinline__ float lrelu(float x) { return x > 0.f ? x : 0.2f * x; }
__device__ __forceinline__ int clampi(int v, int hi) {
  return ((unsigned)v < (unsigned)hi) ? v : 0;
}
// dtype-aware float load: fl=1 -> fp32 source, fl=0 -> bf16 source
__device__ __forceinline__ float ldf(const void* p, size_t i, int fl) {
  return fl ? ((const float*)p)[i] : bf2f(((const u16*)p)[i]);
}

// ---------- sentinel fill (ws too small diagnostic) ----------
__global__ void k_fillf(float* __restrict__ o, int n, float v) {
  int i = blockIdx.x * 256 + threadIdx.x;
  if (i < n) o[i] = v;
}

// ---------- zero scratch ----------
__global__ void k_zero(int* __restrict__ p, int n) {
  int i = blockIdx.x * 256 + threadIdx.x;
  if (i < n) p[i] = 0;
}

// ---------- float dtype detection ----------
__global__ void k_fdetect(const u16* __restrict__ xb, int* __restrict__ fflag) {
  if (blockIdx.x == 0 && threadIdx.x == 0) {
    int huge = 0;
    for (int i = 0; i < 256; ++i) {
      float v = bf2f(xb[i]);
      float a = fabsf(v);
      if (!(a == a) || a > 1e6f) huge++;
    }
    *fflag = (huge > 0) ? 1 : 0;
  }
}

// ---------- int64-vs-int32 edge_index detection ----------
__global__ void k_detect(const int* __restrict__ ei, int* __restrict__ mode) {
  if (blockIdx.x == 0 && threadIdx.x == 0) {
    int nz = 0;
    for (int j = 1; j < 64; j += 2) nz += (ei[j] != 0);
    *mode = (nz == 0) ? 1 : 0;
  }
}

// ---------- small-vector conversions ----------
struct CvtDesc { const void* src; u16* dst; int n; };
struct CvtPack { CvtDesc d[12]; };
__global__ void k_cvt_small(CvtPack p, const int* __restrict__ fflag) {
  int b = blockIdx.x;
  int fl = *fflag;
  const void* src = p.d[b].src;
  u16* dst = p.d[b].dst;
  int n = p.d[b].n;
  for (int i = threadIdx.x; i < n; i += 64)
    dst[i] = fl ? f2bf(((const float*)src)[i]) : ((const u16*)src)[i];
}

// ---------- CSR build: rank pass (the ONLY atomic pass, 1 atomic/edge) ----------
__global__ void k_rank(const int* __restrict__ ei, const int* __restrict__ mode,
                       int* __restrict__ cnt, int* __restrict__ rank, int E_) {
  int e = blockIdx.x * 256 + threadIdx.x;
  if (e >= E_) return;
  int m_ = *mode;
  int d = m_ ? ei[2 * (size_t)(E_ + e)] : ei[E_ + e];
  d = clampi(d, NN);
  rank[e] = atomicAdd(&cnt[d], 1);
}

__global__ void k_bsum(const int* __restrict__ cnt, int* __restrict__ bsum, int n) {
  int b = blockIdx.x, t = threadIdx.x;
  int i0 = b * 1024 + t * 4;
  int s = 0;
#pragma unroll
  for (int j = 0; j < 4; ++j) { int i = i0 + j; if (i < n) s += cnt[i]; }
  for (int off = 32; off; off >>= 1) s += __shfl_xor(s, off);
  __shared__ int wt[4];
  int lane = t & 63, w = t >> 6;
  if (lane == 0) wt[w] = s;
  __syncthreads();
  if (t == 0) bsum[b] = wt[0] + wt[1] + wt[2] + wt[3];
}

__global__ void k_scanb(const int* __restrict__ bsum, int* __restrict__ boff, int nchunks) {
  int t = threadIdx.x;
  int lane = t & 63, w = t >> 6;
  int v = (t < nchunks) ? bsum[t] : 0;
  int sc = v;
  for (int off = 1; off < 64; off <<= 1) { int o = __shfl_up(sc, off); if (lane >= off) sc += o; }
  __shared__ int w0tot;
  if (w == 0 && lane == 63) w0tot = sc;
  __syncthreads();
  int incl = sc + (w ? w0tot : 0);
  if (t < nchunks) boff[t] = incl - v;
}

__global__ void k_scan_chunk(const int* __restrict__ cnt, const int* __restrict__ boff,
                             int* __restrict__ row_off, int n, int etot) {
  int b = blockIdx.x, t = threadIdx.x;
  int i0 = b * 1024 + t * 4;
  int v[4]; int s = 0;
#pragma unroll
  for (int j = 0; j < 4; ++j) { int i = i0 + j; v[j] = (i < n) ? cnt[i] : 0; s += v[j]; }
  int lane = t & 63, w = t >> 6;
  int sc = s;
  for (int off = 1; off < 64; off <<= 1) { int o = __shfl_up(sc, off); if (lane >= off) sc += o; }
  __shared__ int wt[4];
  if (lane == 63) wt[w] = sc;
  __syncthreads();
  int woff = 0;
  for (int k = 0; k < w; ++k) woff += wt[k];
  int ex = boff[b] + woff + sc - s;
#pragma unroll
  for (int j = 0; j < 4; ++j) { int i = i0 + j; if (i < n) row_off[i] = ex; ex += v[j]; }
  if (b == 0 && t == 0) row_off[n] = etot;
}

// ---------- CSR build: deterministic placement (NO atomics) ----------
__global__ void k_place(const int* __restrict__ ei, const int* __restrict__ mode,
                        const void* __restrict__ ew, const int* __restrict__ fflag,
                        const int* __restrict__ row_off, const int* __restrict__ rank,
                        int* __restrict__ esrc, u16* __restrict__ eww, int E_) {
  int e = blockIdx.x * 256 + threadIdx.x;
  if (e >= E_) return;
  int m_ = *mode;
  int s = m_ ? ei[2 * (size_t)e] : ei[e];
  int d = m_ ? ei[2 * (size_t)(E_ + e)] : ei[E_ + e];
  s = clampi(s, NN);
  d = clampi(d, NN);
  int p = row_off[d] + rank[e];
  if (p >= 0 && p < E_) {
    esrc[p] = s;
    eww[p] = f2bf(ldf(ew, e, *fflag));
  }
}

// ---------- self-loop attr = mean incoming weight, from CSR (no atomics) ----------
__global__ void k_loop2(const int* __restrict__ row_off, const u16* __restrict__ eww,
                        float* __restrict__ la, int n) {
  int i = blockIdx.x * 256 + threadIdx.x;
  if (i >= n) return;
  int b = row_off[i], e = row_off[i + 1];
  float s = 0.f;
  for (int j = b; j < e; ++j) s += bf2f(eww[j]);
  la[i] = (e > b) ? s / (float)(e - b) : 0.f;
}

// ---------- dtype-aware weight transpose: WT[m][128+k] layout ----------
__global__ void k_tr(const void* __restrict__ W, const int* __restrict__ fflag,
                     u16* __restrict__ WT, int M) {
  int i = blockIdx.x * 256 + threadIdx.x;
  if (i >= 128 * M) return;
  int k = i / M, m = i % M;
  WT[m * 128 + k] = f2bf(ldf(W, i, *fflag));
}

// ---------- c = dot(We[0,:], a_e) per layer ----------
__global__ void k_dots(const void* We0, const void* ae0, const void* We1, const void* ae1,
                       const void* Wem, const void* aem, const int* __restrict__ fflag,
                       float* c) {
  int b = blockIdx.x;
  const void *w_, *a_; int m;
  if (b == 0)      { w_ = We0; a_ = ae0; m = 128; }
  else if (b == 1) { w_ = We1; a_ = ae1; m = 128; }
  else             { w_ = Wem; a_ = aem; m = 64; }
  int lane = threadIdx.x;
  int fl = *fflag;
  float s = 0.f;
  for (int j = lane; j < m; j += 64) s += ldf(w_, j, fl) * ldf(a_, j, fl);
  for (int off = 32; off; off >>= 1) s += __shfl_xor(s, off);
  if (lane == 0) { c[b] = s; if (b == 0) c[3] = 0.f; }
}

// ---------- GEMM: xl = A @ W (+ logit epilogues) ----------
// FLEXA: A may be fp32 (runtime fflag). DUAL: cols 0-63 -> asrcA, 64-127 -> asrcB.
template<bool FLEXA, bool DUAL>
__global__ __launch_bounds__(256) void k_gemm(
    const void* __restrict__ Araw, const int* __restrict__ fflag,
    const u16* __restrict__ WT,
    const u16* __restrict__ avs, const u16* __restrict__ avd,
    u16* __restrict__ xl,
    float* __restrict__ asrcA, float* __restrict__ adstA,
    float* __restrict__ asrcB, float* __restrict__ adstB, int n) {
  const int K = 128;
  int lane = threadIdx.x & 63;
  int wave = threadIdx.x >> 6;
  int quad = lane >> 4;
  int l16 = lane & 15;
  int r0 = (blockIdx.x * 4 + wave) * 16;
  if (r0 >= n) return;
  int arow = r0 + l16; if (arow >= n) arow = n - 1;
  bf16x8 afr[4];
  int fl = FLEXA ? fflag[0] : 0;
  if (FLEXA && fl) {
    const float* af = (const float*)Araw + (size_t)arow * K + quad * 8;
#pragma unroll
    for (int kb = 0; kb < 4; ++kb) {
      float4 f0 = *(const float4*)(af + kb * 32);
      float4 f1 = *(const float4*)(af + kb * 32 + 4);
      union { bf16x8 v; u16 s[8]; } t;
      t.s[0] = f2bf(f0.x); t.s[1] = f2bf(f0.y); t.s[2] = f2bf(f0.z); t.s[3] = f2bf(f0.w);
      t.s[4] = f2bf(f1.x); t.s[5] = f2bf(f1.y); t.s[6] = f2bf(f1.z); t.s[7] = f2bf(f1.w);
      afr[kb] = t.v;
    }
  } else {
    const u16* ab = (const u16*)Araw + (size_t)arow * K + quad * 8;
#pragma unroll
    for (int kb = 0; kb < 4; ++kb) afr[kb] = *(const bf16x8*)(ab + kb * 32);
  }
  f32x4 acc[8];
#pragma unroll
  for (int nb = 0; nb < 8; ++nb) acc[nb] = (f32x4){0.f, 0.f, 0.f, 0.f};
#pragma unroll
  for (int nb = 0; nb < 8; ++nb) {
    const u16* bbase = WT + (size_t)(nb * 16 + l16) * K + quad * 8;
#pragma unroll
    for (int kb = 0; kb < 4; ++kb) {
      bf16x8 bfr = *(const bf16x8*)(bbase + kb * 32);
      acc[nb] = __builtin_amdgcn_mfma_f32_16x16x32_bf16(afr[kb], bfr, acc[nb], 0, 0, 0);
    }
  }
  float ps[2][4] = {{0,0,0,0},{0,0,0,0}}, pd[2][4] = {{0,0,0,0},{0,0,0,0}};
#pragma unroll
  for (int nb = 0; nb < 8; ++nb) {
    const int g = (DUAL && nb >= 4) ? 1 : 0;
    int col = nb * 16 + l16;
    float vs = bf2f(avs[col]), vd = bf2f(avd[col]);
#pragma unroll
    for (int r = 0; r < 4; ++r) {
      int row = r0 + quad * 4 + r;
      float v = acc[nb][r];
      if (row < n) xl[(size_t)row * 128 + col] = f2bf(v);
      ps[g][r] += v * vs;
      pd[g][r] += v * vd;
    }
  }
#pragma unroll
  for (int off = 1; off < 16; off <<= 1) {
#pragma unroll
    for (int r = 0; r < 4; ++r) {
      ps[0][r] += __shfl_xor(ps[0][r], off);
      pd[0][r] += __shfl_xor(pd[0][r], off);
      if (DUAL) {
        ps[1][r] += __shfl_xor(ps[1][r], off);
        pd[1][r] += __shfl_xor(pd[1][r], off);
      }
    }
  }
  if (l16 == 0) {
#pragma unroll
    for (int r = 0; r < 4; ++r) {
      int row = r0 + quad * 4 + r;
      if (row < n) {
        asrcA[row] = ps[0][r]; adstA[row] = pd[0][r];
        if (DUAL) { asrcB[row] = ps[1][r]; adstB[row] = pd[1][r]; }
      }
    }
  }
}

// ---------- softmax coefficients: wave/node, lane-parallel over edges ----------
template<bool HASE>
__global__ __launch_bounds__(256) void k_coef(
    const int* __restrict__ row_off, const int* __restrict__ esrc,
    const u16* __restrict__ eww,
    const float* __restrict__ asrc, const float* __restrict__ adst,
    const float* __restrict__ la, const float* __restrict__ cptr,
    float* __restrict__ pcoef, float2* __restrict__ nodec, int n) {
  int wid = (blockIdx.x * blockDim.x + threadIdx.x) >> 6;
  if (wid >= n) return;
  int d = __builtin_amdgcn_readfirstlane(wid);
  int lane = threadIdx.x & 63;
  float c = HASE ? cptr[0] : 0.f;
  float ad = adst[d];
  float aL = lrelu(asrc[d] + ad + (HASE ? c * la[d] : 0.f));
  int beg = row_off[d], end = row_off[d + 1];
  float m = aL;
  for (int base = beg; base < end; base += 64) {
    int i = base + lane;
    float al = -3e38f;
    if (i < end) {
      int s = esrc[i];
      al = lrelu(asrc[s] + ad + (HASE ? c * bf2f(eww[i]) : 0.f));
    }
#pragma unroll
    for (int off = 32; off; off >>= 1) al = fmaxf(al, __shfl_xor(al, off));
    m = fmaxf(m, al);
  }
  float lsum = 0.f;
  for (int base = beg; base < end; base += 64) {
    int i = base + lane;
    float p = 0.f;
    if (i < end) {
      int s = esrc[i];
      float al = lrelu(asrc[s] + ad + (HASE ? c * bf2f(eww[i]) : 0.f));
      p = __expf(al - m);
      pcoef[i] = p;
    }
    lsum += p;
  }
#pragma unroll
  for (int off = 32; off; off >>= 1) lsum += __shfl_xor(lsum, off);
  float selfp = __expf(aL - m);
  if (lane == 0) nodec[d] = make_float2(selfp, 1.f / (lsum + selfp));
}

// ---------- feature aggregation (layers): wave/node, bf16 out, ReLU ----------
__global__ __launch_bounds__(256) void k_feat(
    const int* __restrict__ row_off, const int* __restrict__ esrc,
    const float* __restrict__ pcoef, const float2* __restrict__ nodec,
    const u16* __restrict__ xl, const u16* __restrict__ bias,
    u16* __restrict__ out, int n) {
  int wid = (blockIdx.x * blockDim.x + threadIdx.x) >> 6;
  if (wid >= n) return;
  int d = __builtin_amdgcn_readfirstlane(wid);
  int lane = threadIdx.x & 63;
  float2 nc = nodec[d];
  unsigned su = *(const unsigned*)(xl + (size_t)d * 128 + 2 * lane);
  float a0 = nc.x * lo_f(su), a1 = nc.x * hi_f(su);
  float b0 = 0.f, b1 = 0.f;
  int beg = row_off[d], end = row_off[d + 1];
  int i = beg;
  for (; i + 2 <= end; i += 2) {
    int s0 = esrc[i], s1 = esrc[i + 1];
    float p0 = pcoef[i], p1 = pcoef[i + 1];
    unsigned u0 = *(const unsigned*)(xl + (size_t)s0 * 128 + 2 * lane);
    unsigned u1 = *(const unsigned*)(xl + (size_t)s1 * 128 + 2 * lane);
    a0 = fmaf(p0, lo_f(u0), a0); a1 = fmaf(p0, hi_f(u0), a1);
    b0 = fmaf(p1, lo_f(u1), b0); b1 = fmaf(p1, hi_f(u1), b1);
  }
  if (i < end) {
    int s0 = esrc[i]; float p0 = pcoef[i];
    unsigned u0 = *(const unsigned*)(xl + (size_t)s0 * 128 + 2 * lane);
    a0 = fmaf(p0, lo_f(u0), a0); a1 = fmaf(p0, hi_f(u0), a1);
  }
  a0 += b0; a1 += b1;
  float o0 = fmaxf(fmaf(a0, nc.y, bf2f(bias[2 * lane])), 0.f);
  float o1 = fmaxf(fmaf(a1, nc.y, bf2f(bias[2 * lane + 1])), 0.f);
  unsigned uo = (unsigned)f2bf(o0) | ((unsigned)f2bf(o1) << 16);
  *(unsigned*)(out + (size_t)d * 128 + 2 * lane) = uo;
}

// ---------- fused head aggregation: lanes 0-31 mu, 32-63 logstd, fp32 out ----------
__global__ __launch_bounds__(256) void k_feath(
    const int* __restrict__ row_off, const int* __restrict__ esrc,
    const float* __restrict__ pcA, const float2* __restrict__ ncA,
    const float* __restrict__ pcB, const float2* __restrict__ ncB,
    const u16* __restrict__ xl, const u16* __restrict__ bias,
    float* __restrict__ outf, int n) {
  int wid = (blockIdx.x * blockDim.x + threadIdx.x) >> 6;
  if (wid >= n) return;
  int d = __builtin_amdgcn_readfirstlane(wid);
  int lane = threadIdx.x & 63;
  bool isMu = lane < 32;
  const float* pc = isMu ? pcA : pcB;
  float2 nc = isMu ? ncA[d] : ncB[d];
  unsigned su = *(const unsigned*)(xl + (size_t)d * 128 + 2 * lane);
  float a0 = nc.x * lo_f(su), a1 = nc.x * hi_f(su);
  float b0 = 0.f, b1 = 0.f;
  int beg = row_off[d], end = row_off[d + 1];
  int i = beg;
  for (; i + 2 <= end; i += 2) {
    int s0 = esrc[i], s1 = esrc[i + 1];
    float p0 = pc[i], p1 = pc[i + 1];
    unsigned u0 = *(const unsigned*)(xl + (size_t)s0 * 128 + 2 * lane);
    unsigned u1 = *(const unsigned*)(xl + (size_t)s1 * 128 + 2 * lane);
    a0 = fmaf(p0, lo_f(u0), a0); a1 = fmaf(p0, hi_f(u0), a1);
    b0 = fmaf(p1, lo_f(u1), b0); b1 = fmaf(p1, hi_f(u1), b1);
  }
  if (i < end) {
    int s0 = esrc[i]; float p0 = pc[i];
    unsigned u0 = *(const unsigned*)(xl + (size_t)s0 * 128 + 2 * lane);
    a0 = fmaf(p0, lo_f(u0), a0); a1 = fmaf(p0, hi_f(u0), a1);
  }
  a0 += b0; a1 += b1;
  int col0 = 2 * lane;
  float o0 = fmaf(a0, nc.y, bf2f(bias[col0]));
  float o1 = fmaf(a1, nc.y, bf2f(bias[col0 + 1]));
  float* ob = isMu ? (outf + (size_t)d * 64 + col0)
                   : (outf + (size_t)NN * 64 + (size_t)d * 64 + (col0 - 64));
  ob[0] = o0; ob[1] = o1;
}

extern "C" void kernel_launch(void* const* d_in, const int* in_sizes, int n_in,
                              void* d_out, int out_size, void* d_ws, size_t ws_size,
                              hipStream_t stream) {
  (void)in_sizes; (void)n_in;
  const int* ei = (const int*)d_in[1];
  float* outf = (float*)d_out;  // fp32 output

  // d_out halves double as bf16 h-buffers (dead before fp32 heads overwrite):
  u16* regionA = (u16*)d_out;                     // h1
  u16* regionB = (u16*)d_out + (size_t)NN * 128;  // h0
  // edge_index buffer is dead after CSR build -> reuse for softmax coefs
  float* pcA = (float*)d_in[1];
  float* pcB = pcA + EE;

  char* p = (char*)d_ws;
  auto alloc = [&](size_t bytes) -> char* {
    char* r = p; p += (bytes + 255) & ~(size_t)255; return r;
  };
  char* z0      = p;
  int*   cnt    = (int*)alloc(NN * 4);
  size_t zbytes = (size_t)(p - z0);
  int*   row_off= (int*)alloc((NN + 1) * 4);
  int*   bsum   = (int*)alloc(512);
  int*   boff   = (int*)alloc(512);
  int*   mode   = (int*)alloc(256);
  int*   fflag  = (int*)alloc(256);
  float* la     = (float*)alloc(NN * 4);
  float* asrcA  = (float*)alloc(NN * 4);
  float* adstA  = (float*)alloc(NN * 4);
  float* asrcB  = (float*)alloc(NN * 4);
  float* adstB  = (float*)alloc(NN * 4);
  int*   esrc   = (int*)alloc((size_t)EE * 4);
  u16*   eww    = (u16*)alloc((size_t)EE * 2);
  u16*   WT0    = (u16*)alloc(128 * 128 * 2);
  u16*   WT1    = (u16*)alloc(128 * 128 * 2);
  u16*   WTh    = (u16*)alloc(128 * 128 * 2);
  float* cvals  = (float*)alloc(16);
  u16*   vecc   = (u16*)alloc(9 * 256);
  float2* ncA   = (float2*)alloc((size_t)NN * 8);
  float2* ncB   = (float2*)alloc((size_t)NN * 8);
  u16*   xl     = (u16*)alloc((size_t)NN * 128 * 2);  // 25.6 MB

  // rank[e] aliases xl: dead until first k_gemm, consumed by k_place before that.
  int* rank = (int*)xl;  // 6.4 MB <= 25.6 MB

  size_t NEED = (size_t)(p - (char*)d_ws);  // ~39.7 MB
  if (ws_size < NEED) {
    k_fillf<<<(out_size + 255) / 256, 256, 0, stream>>>(outf, out_size, 0.125f);
    return;
  }

  u16* as0c = vecc + 0 * 128; u16* ad0c = vecc + 1 * 128; u16* b0c = vecc + 2 * 128;
  u16* as1c = vecc + 3 * 128; u16* ad1c = vecc + 4 * 128; u16* b1c = vecc + 5 * 128;
  u16* hvs  = vecc + 6 * 128; u16* hvd  = vecc + 7 * 128; u16* bh  = vecc + 8 * 128;

  // ---- detection ----
  k_fdetect<<<1, 64, 0, stream>>>((const u16*)d_in[0], fflag);
  k_detect<<<1, 64, 0, stream>>>(ei, mode);

  // ---- small vectors -> bf16 ws ----
  CvtPack pk;
  pk.d[0]  = {d_in[4],  as0c, 128};
  pk.d[1]  = {d_in[5],  ad0c, 128};
  pk.d[2]  = {d_in[8],  b0c,  128};
  pk.d[3]  = {d_in[10], as1c, 128};
  pk.d[4]  = {d_in[11], ad1c, 128};
  pk.d[5]  = {d_in[14], b1c,  128};
  pk.d[6]  = {d_in[16], hvs,      64};  // asm -> hvs[0:64)
  pk.d[7]  = {d_in[22], hvs + 64, 64};  // asl -> hvs[64:128)
  pk.d[8]  = {d_in[17], hvd,      64};  // adm
  pk.d[9]  = {d_in[23], hvd + 64, 64};  // adl
  pk.d[10] = {d_in[20], bh,       64};  // bm
  pk.d[11] = {d_in[24], bh + 64,  64};  // bl
  k_cvt_small<<<12, 64, 0, stream>>>(pk, fflag);

  const int nz = (int)(zbytes / 4);
  k_zero<<<(nz + 255) / 256, 256, 0, stream>>>((int*)z0, nz);

  const int Eblocks = (EE + 255) / 256;
  const int nchunks = (NN + 1023) / 1024;
  // ---- CSR build: 1 atomic/edge total (rank), then atomic-free placement ----
  k_rank<<<Eblocks, 256, 0, stream>>>(ei, mode, cnt, rank, EE);
  k_bsum<<<nchunks, 256, 0, stream>>>(cnt, bsum, NN);
  k_scanb<<<1, 128, 0, stream>>>(bsum, boff, nchunks);
  k_scan_chunk<<<nchunks, 256, 0, stream>>>(cnt, boff, row_off, NN, EE);
  k_place<<<Eblocks, 256, 0, stream>>>(ei, mode, d_in[2], fflag, row_off, rank, esrc, eww, EE);
  k_loop2<<<(NN + 255) / 256, 256, 0, stream>>>(row_off, eww, la, NN);
  k_tr<<<64, 256, 0, stream>>>(d_in[3],  fflag, WT0, 128);
  k_tr<<<64, 256, 0, stream>>>(d_in[9],  fflag, WT1, 128);
  k_tr<<<32, 256, 0, stream>>>(d_in[15], fflag, WTh, 64);             // Wm -> rows 0-63
  k_tr<<<32, 256, 0, stream>>>(d_in[21], fflag, WTh + 64 * 128, 64);  // Wl -> rows 64-127
  k_dots<<<3, 64, 0, stream>>>(d_in[7], d_in[6], d_in[13], d_in[12], d_in[19], d_in[18],
                               fflag, cvals);

  const int gblocks = (((NN + 15) / 16) + 3) / 4;
  const int eblocks = (int)(((size_t)NN * 64 + 255) / 256);

  // layer 0: x (fp32|bf16) -> xl -> h0(regionB)   [k_gemm writes xl, rank now dead]
  k_gemm<true, false><<<gblocks, 256, 0, stream>>>(d_in[0], fflag, WT0, as0c, ad0c,
                                                   xl, asrcA, adstA, nullptr, nullptr, NN);
  k_coef<true><<<eblocks, 256, 0, stream>>>(row_off, esrc, eww, asrcA, adstA, la,
                                            cvals + 0, pcA, ncA, NN);
  k_feat<<<eblocks, 256, 0, stream>>>(row_off, esrc, pcA, ncA, xl, b0c, regionB, NN);
  // layer 1: h0 -> xl -> h1(regionA)
  k_gemm<false, false><<<gblocks, 256, 0, stream>>>(regionB, fflag, WT1, as1c, ad1c,
                                                    xl, asrcA, adstA, nullptr, nullptr, NN);
  k_coef<true><<<eblocks, 256, 0, stream>>>(row_off, esrc, eww, asrcA, adstA, la,
                                            cvals + 1, pcA, ncA, NN);
  k_feat<<<eblocks, 256, 0, stream>>>(row_off, esrc, pcA, ncA, xl, b1c, regionA, NN);
  // heads: h1 -> xl[cols 0-63 mu | 64-127 logstd] -> fp32 mu/logstd
  k_gemm<false, true><<<gblocks, 256, 0, stream>>>(regionA, fflag, WTh, hvs, hvd,
                                                   xl, asrcA, adstA, asrcB, adstB, NN);
  k_coef<true><<<eblocks, 256, 0, stream>>>(row_off, esrc, eww, asrcA, adstA, la,
                                            cvals + 2, pcA, ncA, NN);
  k_coef<false><<<eblocks, 256, 0, stream>>>(row_off, esrc, eww, asrcB, adstB, la,
                                             cvals + 3, pcB, ncB, NN);
  k_feath<<<eblocks, 256, 0, stream>>>(row_off, esrc, pcA, ncA, pcB, ncB, xl, bh, outf, NN);
}

// Round 3
// 617.755 us; speedup vs baseline: 1.4309x; 1.1897x over previous
//
#include <hip/hip_runtime.h>

#define NN 100000
#define EE 1600000

typedef __attribute__((ext_vector_type(8))) __bf16 bf16x8;
typedef __attribute__((ext_vector_type(4))) float f32x4;
typedef unsigned short u16;

__device__ __forceinline__ float bf2f(u16 v) {
  union { unsigned u; float f; } x; x.u = ((unsigned)v) << 16; return x.f;
}
__device__ __forceinline__ u16 f2bf(float f) {
  union { unsigned u; float f; } x; x.f = f;
  x.u += 0x7fffu + ((x.u >> 16) & 1u);
  return (u16)(x.u >> 16);
}
__device__ __forceinline__ float lo_f(unsigned u) {
  union { unsigned u; float f; } x; x.u = u << 16; return x.f;
}
__device__ __forceinline__ float hi_f(unsigned u) {
  union { unsigned u; float f; } x; x.u = u & 0xffff0000u; return x.f;
}
__device__ __forceinline__ float lrelu(float x) { return x > 0.f ? x : 0.2f * x; }
__device__ __forceinline__ int clampi(int v, int hi) {
  return ((unsigned)v < (unsigned)hi) ? v : 0;
}
// dtype-aware float load: fl=1 -> fp32 source, fl=0 -> bf16 source
__device__ __forceinline__ float ldf(const void* p, size_t i, int fl) {
  return fl ? ((const float*)p)[i] : bf2f(((const u16*)p)[i]);
}

// ---------- sentinel fill (ws too small diagnostic) ----------
__global__ void k_fillf(float* __restrict__ o, int n, float v) {
  int i = blockIdx.x * 256 + threadIdx.x;
  if (i < n) o[i] = v;
}

// ---------- zero scratch ----------
__global__ void k_zero(int* __restrict__ p, int n) {
  int i = blockIdx.x * 256 + threadIdx.x;
  if (i < n) p[i] = 0;
}

// ---------- float dtype detection ----------
__global__ void k_fdetect(const u16* __restrict__ xb, int* __restrict__ fflag) {
  if (blockIdx.x == 0 && threadIdx.x == 0) {
    int huge = 0;
    for (int i = 0; i < 256; ++i) {
      float v = bf2f(xb[i]);
      float a = fabsf(v);
      if (!(a == a) || a > 1e6f) huge++;
    }
    *fflag = (huge > 0) ? 1 : 0;
  }
}

// ---------- int64-vs-int32 edge_index detection ----------
__global__ void k_detect(const int* __restrict__ ei, int* __restrict__ mode) {
  if (blockIdx.x == 0 && threadIdx.x == 0) {
    int nz = 0;
    for (int j = 1; j < 64; j += 2) nz += (ei[j] != 0);
    *mode = (nz == 0) ? 1 : 0;
  }
}

// ---------- small-vector conversions ----------
struct CvtDesc { const void* src; u16* dst; int n; };
struct CvtPack { CvtDesc d[12]; };
__global__ void k_cvt_small(CvtPack p, const int* __restrict__ fflag) {
  int b = blockIdx.x;
  int fl = *fflag;
  const void* src = p.d[b].src;
  u16* dst = p.d[b].dst;
  int n = p.d[b].n;
  for (int i = threadIdx.x; i < n; i += 64)
    dst[i] = fl ? f2bf(((const float*)src)[i]) : ((const u16*)src)[i];
}

// ---------- CSR build: rank pass (the ONLY atomic pass, 1 atomic/edge) ----------
__global__ void k_rank(const int* __restrict__ ei, const int* __restrict__ mode,
                       int* __restrict__ cnt, int* __restrict__ rank, int E_) {
  int e = blockIdx.x * 256 + threadIdx.x;
  if (e >= E_) return;
  int m_ = *mode;
  int d = m_ ? ei[2 * (size_t)(E_ + e)] : ei[E_ + e];
  d = clampi(d, NN);
  rank[e] = atomicAdd(&cnt[d], 1);
}

__global__ void k_bsum(const int* __restrict__ cnt, int* __restrict__ bsum, int n) {
  int b = blockIdx.x, t = threadIdx.x;
  int i0 = b * 1024 + t * 4;
  int s = 0;
#pragma unroll
  for (int j = 0; j < 4; ++j) { int i = i0 + j; if (i < n) s += cnt[i]; }
  for (int off = 32; off; off >>= 1) s += __shfl_xor(s, off);
  __shared__ int wt[4];
  int lane = t & 63, w = t >> 6;
  if (lane == 0) wt[w] = s;
  __syncthreads();
  if (t == 0) bsum[b] = wt[0] + wt[1] + wt[2] + wt[3];
}

__global__ void k_scanb(const int* __restrict__ bsum, int* __restrict__ boff, int nchunks) {
  int t = threadIdx.x;
  int lane = t & 63, w = t >> 6;
  int v = (t < nchunks) ? bsum[t] : 0;
  int sc = v;
  for (int off = 1; off < 64; off <<= 1) { int o = __shfl_up(sc, off); if (lane >= off) sc += o; }
  __shared__ int w0tot;
  if (w == 0 && lane == 63) w0tot = sc;
  __syncthreads();
  int incl = sc + (w ? w0tot : 0);
  if (t < nchunks) boff[t] = incl - v;
}

__global__ void k_scan_chunk(const int* __restrict__ cnt, const int* __restrict__ boff,
                             int* __restrict__ row_off, int n, int etot) {
  int b = blockIdx.x, t = threadIdx.x;
  int i0 = b * 1024 + t * 4;
  int v[4]; int s = 0;
#pragma unroll
  for (int j = 0; j < 4; ++j) { int i = i0 + j; v[j] = (i < n) ? cnt[i] : 0; s += v[j]; }
  int lane = t & 63, w = t >> 6;
  int sc = s;
  for (int off = 1; off < 64; off <<= 1) { int o = __shfl_up(sc, off); if (lane >= off) sc += o; }
  __shared__ int wt[4];
  if (lane == 63) wt[w] = sc;
  __syncthreads();
  int woff = 0;
  for (int k = 0; k < w; ++k) woff += wt[k];
  int ex = boff[b] + woff + sc - s;
#pragma unroll
  for (int j = 0; j < 4; ++j) { int i = i0 + j; if (i < n) row_off[i] = ex; ex += v[j]; }
  if (b == 0 && t == 0) row_off[n] = etot;
}

// ---------- CSR build: deterministic placement (NO atomics) ----------
__global__ void k_place(const int* __restrict__ ei, const int* __restrict__ mode,
                        const void* __restrict__ ew, const int* __restrict__ fflag,
                        const int* __restrict__ row_off, const int* __restrict__ rank,
                        int* __restrict__ esrc, u16* __restrict__ eww, int E_) {
  int e = blockIdx.x * 256 + threadIdx.x;
  if (e >= E_) return;
  int m_ = *mode;
  int s = m_ ? ei[2 * (size_t)e] : ei[e];
  int d = m_ ? ei[2 * (size_t)(E_ + e)] : ei[E_ + e];
  s = clampi(s, NN);
  d = clampi(d, NN);
  int p = row_off[d] + rank[e];
  if (p >= 0 && p < E_) {
    esrc[p] = s;
    eww[p] = f2bf(ldf(ew, e, *fflag));
  }
}

// ---------- self-loop attr = mean incoming weight, from CSR (no atomics) ----------
__global__ void k_loop2(const int* __restrict__ row_off, const u16* __restrict__ eww,
                        float* __restrict__ la, int n) {
  int i = blockIdx.x * 256 + threadIdx.x;
  if (i >= n) return;
  int b = row_off[i], e = row_off[i + 1];
  float s = 0.f;
  for (int j = b; j < e; ++j) s += bf2f(eww[j]);
  la[i] = (e > b) ? s / (float)(e - b) : 0.f;
}

// ---------- dtype-aware weight transpose: WT[m][128+k] layout ----------
__global__ void k_tr(const void* __restrict__ W, const int* __restrict__ fflag,
                     u16* __restrict__ WT, int M) {
  int i = blockIdx.x * 256 + threadIdx.x;
  if (i >= 128 * M) return;
  int k = i / M, m = i % M;
  WT[m * 128 + k] = f2bf(ldf(W, i, *fflag));
}

// ---------- c = dot(We[0,:], a_e) per layer ----------
__global__ void k_dots(const void* We0, const void* ae0, const void* We1, const void* ae1,
                       const void* Wem, const void* aem, const int* __restrict__ fflag,
                       float* c) {
  int b = blockIdx.x;
  const void *w_, *a_; int m;
  if (b == 0)      { w_ = We0; a_ = ae0; m = 128; }
  else if (b == 1) { w_ = We1; a_ = ae1; m = 128; }
  else             { w_ = Wem; a_ = aem; m = 64; }
  int lane = threadIdx.x;
  int fl = *fflag;
  float s = 0.f;
  for (int j = lane; j < m; j += 64) s += ldf(w_, j, fl) * ldf(a_, j, fl);
  for (int off = 32; off; off >>= 1) s += __shfl_xor(s, off);
  if (lane == 0) { c[b] = s; if (b == 0) c[3] = 0.f; }
}

// ---------- GEMM: xl = A @ W (+ logit epilogues) ----------
// FLEXA: A may be fp32 (runtime fflag). DUAL: cols 0-63 -> asrcA, 64-127 -> asrcB.
template<bool FLEXA, bool DUAL>
__global__ __launch_bounds__(256) void k_gemm(
    const void* __restrict__ Araw, const int* __restrict__ fflag,
    const u16* __restrict__ WT,
    const u16* __restrict__ avs, const u16* __restrict__ avd,
    u16* __restrict__ xl,
    float* __restrict__ asrcA, float* __restrict__ adstA,
    float* __restrict__ asrcB, float* __restrict__ adstB, int n) {
  const int K = 128;
  int lane = threadIdx.x & 63;
  int wave = threadIdx.x >> 6;
  int quad = lane >> 4;
  int l16 = lane & 15;
  int r0 = (blockIdx.x * 4 + wave) * 16;
  if (r0 >= n) return;
  int arow = r0 + l16; if (arow >= n) arow = n - 1;
  bf16x8 afr[4];
  int fl = FLEXA ? fflag[0] : 0;
  if (FLEXA && fl) {
    const float* af = (const float*)Araw + (size_t)arow * K + quad * 8;
#pragma unroll
    for (int kb = 0; kb < 4; ++kb) {
      float4 f0 = *(const float4*)(af + kb * 32);
      float4 f1 = *(const float4*)(af + kb * 32 + 4);
      union { bf16x8 v; u16 s[8]; } t;
      t.s[0] = f2bf(f0.x); t.s[1] = f2bf(f0.y); t.s[2] = f2bf(f0.z); t.s[3] = f2bf(f0.w);
      t.s[4] = f2bf(f1.x); t.s[5] = f2bf(f1.y); t.s[6] = f2bf(f1.z); t.s[7] = f2bf(f1.w);
      afr[kb] = t.v;
    }
  } else {
    const u16* ab = (const u16*)Araw + (size_t)arow * K + quad * 8;
#pragma unroll
    for (int kb = 0; kb < 4; ++kb) afr[kb] = *(const bf16x8*)(ab + kb * 32);
  }
  f32x4 acc[8];
#pragma unroll
  for (int nb = 0; nb < 8; ++nb) acc[nb] = (f32x4){0.f, 0.f, 0.f, 0.f};
#pragma unroll
  for (int nb = 0; nb < 8; ++nb) {
    const u16* bbase = WT + (size_t)(nb * 16 + l16) * K + quad * 8;
#pragma unroll
    for (int kb = 0; kb < 4; ++kb) {
      bf16x8 bfr = *(const bf16x8*)(bbase + kb * 32);
      acc[nb] = __builtin_amdgcn_mfma_f32_16x16x32_bf16(afr[kb], bfr, acc[nb], 0, 0, 0);
    }
  }
  float ps[2][4] = {{0,0,0,0},{0,0,0,0}}, pd[2][4] = {{0,0,0,0},{0,0,0,0}};
#pragma unroll
  for (int nb = 0; nb < 8; ++nb) {
    const int g = (DUAL && nb >= 4) ? 1 : 0;
    int col = nb * 16 + l16;
    float vs = bf2f(avs[col]), vd = bf2f(avd[col]);
#pragma unroll
    for (int r = 0; r < 4; ++r) {
      int row = r0 + quad * 4 + r;
      float v = acc[nb][r];
      if (row < n) xl[(size_t)row * 128 + col] = f2bf(v);
      ps[g][r] += v * vs;
      pd[g][r] += v * vd;
    }
  }
#pragma unroll
  for (int off = 1; off < 16; off <<= 1) {
#pragma unroll
    for (int r = 0; r < 4; ++r) {
      ps[0][r] += __shfl_xor(ps[0][r], off);
      pd[0][r] += __shfl_xor(pd[0][r], off);
      if (DUAL) {
        ps[1][r] += __shfl_xor(ps[1][r], off);
        pd[1][r] += __shfl_xor(pd[1][r], off);
      }
    }
  }
  if (l16 == 0) {
#pragma unroll
    for (int r = 0; r < 4; ++r) {
      int row = r0 + quad * 4 + r;
      if (row < n) {
        asrcA[row] = ps[0][r]; adstA[row] = pd[0][r];
        if (DUAL) { asrcB[row] = ps[1][r]; adstB[row] = pd[1][r]; }
      }
    }
  }
}

// ---------- FUSED online-softmax + aggregation (layers): wave/node ----------
// Chunk of 64 edges: lanes||edges compute alpha -> wave max/sum with flash
// rescale -> (e,s) to LDS -> lanes||features serial gather (unroll-4).
__global__ __launch_bounds__(256) void k_agg(
    const int* __restrict__ row_off, const int* __restrict__ esrc,
    const u16* __restrict__ eww,
    const float* __restrict__ asrc, const float* __restrict__ adst,
    const float* __restrict__ la, const float* __restrict__ cptr,
    const u16* __restrict__ xl, const u16* __restrict__ bias,
    u16* __restrict__ out, int n) {
  __shared__ float lp[4][64];
  __shared__ int lsv[4][64];
  int wid = (blockIdx.x * blockDim.x + threadIdx.x) >> 6;
  if (wid >= n) return;
  int w = threadIdx.x >> 6;
  int d = __builtin_amdgcn_readfirstlane(wid);
  int lane = threadIdx.x & 63;
  float c = cptr[0];
  float ad = adst[d];
  float aL = lrelu(asrc[d] + ad + c * la[d]);
  float m = aL, den = 1.f;  // self term: exp(aL-m)=1
  unsigned su = *(const unsigned*)(xl + (size_t)d * 128 + 2 * lane);
  float A0 = lo_f(su), A1 = hi_f(su);  // self-weighted (weight 1 at m=aL)
  int beg = row_off[d], end = row_off[d + 1];
  for (int base = beg; base < end; base += 64) {
    int i = base + lane;
    bool v = i < end;
    int s = v ? esrc[i] : 0;
    float al = v ? lrelu(asrc[s] + ad + c * bf2f(eww[i])) : -3e38f;
    float cm = al;
#pragma unroll
    for (int off = 32; off; off >>= 1) cm = fmaxf(cm, __shfl_xor(cm, off));
    if (cm > m) {
      float f = __expf(m - cm);
      A0 *= f; A1 *= f; den *= f;
      m = cm;
    }
    float e = v ? __expf(al - m) : 0.f;
    lp[w][lane] = e; lsv[w][lane] = s;
    float es = e;
#pragma unroll
    for (int off = 32; off; off >>= 1) es += __shfl_xor(es, off);
    den += es;
    int cnt = end - base; if (cnt > 64) cnt = 64;
    float B0 = 0.f, B1 = 0.f, C0 = 0.f, C1 = 0.f, D0 = 0.f, D1 = 0.f;
    int j = 0;
    for (; j + 4 <= cnt; j += 4) {
      float p0 = lp[w][j + 0]; int s0 = lsv[w][j + 0];
      float p1 = lp[w][j + 1]; int s1 = lsv[w][j + 1];
      float p2 = lp[w][j + 2]; int s2 = lsv[w][j + 2];
      float p3 = lp[w][j + 3]; int s3 = lsv[w][j + 3];
      unsigned u0 = *(const unsigned*)(xl + (size_t)s0 * 128 + 2 * lane);
      unsigned u1 = *(const unsigned*)(xl + (size_t)s1 * 128 + 2 * lane);
      unsigned u2 = *(const unsigned*)(xl + (size_t)s2 * 128 + 2 * lane);
      unsigned u3 = *(const unsigned*)(xl + (size_t)s3 * 128 + 2 * lane);
      A0 = fmaf(p0, lo_f(u0), A0); A1 = fmaf(p0, hi_f(u0), A1);
      B0 = fmaf(p1, lo_f(u1), B0); B1 = fmaf(p1, hi_f(u1), B1);
      C0 = fmaf(p2, lo_f(u2), C0); C1 = fmaf(p2, hi_f(u2), C1);
      D0 = fmaf(p3, lo_f(u3), D0); D1 = fmaf(p3, hi_f(u3), D1);
    }
    for (; j < cnt; ++j) {
      float p0 = lp[w][j]; int s0 = lsv[w][j];
      unsigned u0 = *(const unsigned*)(xl + (size_t)s0 * 128 + 2 * lane);
      A0 = fmaf(p0, lo_f(u0), A0); A1 = fmaf(p0, hi_f(u0), A1);
    }
    A0 += B0 + C0 + D0; A1 += B1 + C1 + D1;  // fold before next rescale
  }
  float inv = 1.f / den;
  float o0 = fmaxf(fmaf(A0, inv, bf2f(bias[2 * lane])), 0.f);
  float o1 = fmaxf(fmaf(A1, inv, bf2f(bias[2 * lane + 1])), 0.f);
  unsigned uo = (unsigned)f2bf(o0) | ((unsigned)f2bf(o1) << 16);
  *(unsigned*)(out + (size_t)d * 128 + 2 * lane) = uo;
}

// ---------- FUSED dual-head version: lanes 0-31 mu (edge-attr), 32-63 logstd ----------
__global__ __launch_bounds__(256) void k_aggh(
    const int* __restrict__ row_off, const int* __restrict__ esrc,
    const u16* __restrict__ eww,
    const float* __restrict__ asA, const float* __restrict__ adA,
    const float* __restrict__ asB, const float* __restrict__ adB,
    const float* __restrict__ la, const float* __restrict__ cptr,
    const u16* __restrict__ xl, const u16* __restrict__ bias,
    float* __restrict__ outf, int n) {
  __shared__ float lpA[4][64];
  __shared__ float lpB[4][64];
  __shared__ int lsv[4][64];
  int wid = (blockIdx.x * blockDim.x + threadIdx.x) >> 6;
  if (wid >= n) return;
  int w = threadIdx.x >> 6;
  int d = __builtin_amdgcn_readfirstlane(wid);
  int lane = threadIdx.x & 63;
  bool isMu = lane < 32;
  float c = cptr[0];
  float adAd = adA[d], adBd = adB[d];
  float aLA = lrelu(asA[d] + adAd + c * la[d]);
  float aLB = lrelu(asB[d] + adBd);
  float mA = aLA, mB = aLB, denA = 1.f, denB = 1.f;
  unsigned su = *(const unsigned*)(xl + (size_t)d * 128 + 2 * lane);
  float A0 = lo_f(su), A1 = hi_f(su);  // self weight 1 in each lane's group
  int beg = row_off[d], end = row_off[d + 1];
  for (int base = beg; base < end; base += 64) {
    int i = base + lane;
    bool v = i < end;
    int s = v ? esrc[i] : 0;
    float sa = v ? asA[s] : 0.f, sb = v ? asB[s] : 0.f;
    float alA = v ? lrelu(sa + adAd + c * bf2f(eww[i])) : -3e38f;
    float alB = v ? lrelu(sb + adBd) : -3e38f;
    float cmA = alA, cmB = alB;
#pragma unroll
    for (int off = 32; off; off >>= 1) {
      cmA = fmaxf(cmA, __shfl_xor(cmA, off));
      cmB = fmaxf(cmB, __shfl_xor(cmB, off));
    }
    float fA = 1.f, fB = 1.f;
    if (cmA > mA) { fA = __expf(mA - cmA); mA = cmA; denA *= fA; }
    if (cmB > mB) { fB = __expf(mB - cmB); mB = cmB; denB *= fB; }
    float f = isMu ? fA : fB;
    A0 *= f; A1 *= f;
    float eA = v ? __expf(alA - mA) : 0.f;
    float eB = v ? __expf(alB - mB) : 0.f;
    lpA[w][lane] = eA; lpB[w][lane] = eB; lsv[w][lane] = s;
    float esA = eA, esB = eB;
#pragma unroll
    for (int off = 32; off; off >>= 1) {
      esA += __shfl_xor(esA, off);
      esB += __shfl_xor(esB, off);
    }
    denA += esA; denB += esB;
    const float* lpp = isMu ? lpA[w] : lpB[w];
    int cnt = end - base; if (cnt > 64) cnt = 64;
    float B0 = 0.f, B1 = 0.f, C0 = 0.f, C1 = 0.f, D0 = 0.f, D1 = 0.f;
    int j = 0;
    for (; j + 4 <= cnt; j += 4) {
      float p0 = lpp[j + 0]; int s0 = lsv[w][j + 0];
      float p1 = lpp[j + 1]; int s1 = lsv[w][j + 1];
      float p2 = lpp[j + 2]; int s2 = lsv[w][j + 2];
      float p3 = lpp[j + 3]; int s3 = lsv[w][j + 3];
      unsigned u0 = *(const unsigned*)(xl + (size_t)s0 * 128 + 2 * lane);
      unsigned u1 = *(const unsigned*)(xl + (size_t)s1 * 128 + 2 * lane);
      unsigned u2 = *(const unsigned*)(xl + (size_t)s2 * 128 + 2 * lane);
      unsigned u3 = *(const unsigned*)(xl + (size_t)s3 * 128 + 2 * lane);
      A0 = fmaf(p0, lo_f(u0), A0); A1 = fmaf(p0, hi_f(u0), A1);
      B0 = fmaf(p1, lo_f(u1), B0); B1 = fmaf(p1, hi_f(u1), B1);
      C0 = fmaf(p2, lo_f(u2), C0); C1 = fmaf(p2, hi_f(u2), C1);
      D0 = fmaf(p3, lo_f(u3), D0); D1 = fmaf(p3, hi_f(u3), D1);
    }
    for (; j < cnt; ++j) {
      float p0 = lpp[j]; int s0 = lsv[w][j];
      unsigned u0 = *(const unsigned*)(xl + (size_t)s0 * 128 + 2 * lane);
      A0 = fmaf(p0, lo_f(u0), A0); A1 = fmaf(p0, hi_f(u0), A1);
    }
    A0 += B0 + C0 + D0; A1 += B1 + C1 + D1;
  }
  float inv = isMu ? (1.f / denA) : (1.f / denB);
  int col0 = 2 * lane;
  float o0 = fmaf(A0, inv, bf2f(bias[col0]));
  float o1 = fmaf(A1, inv, bf2f(bias[col0 + 1]));
  float* ob = isMu ? (outf + (size_t)d * 64 + col0)
                   : (outf + (size_t)NN * 64 + (size_t)d * 64 + (col0 - 64));
  ob[0] = o0; ob[1] = o1;
}

extern "C" void kernel_launch(void* const* d_in, const int* in_sizes, int n_in,
                              void* d_out, int out_size, void* d_ws, size_t ws_size,
                              hipStream_t stream) {
  (void)in_sizes; (void)n_in;
  const int* ei = (const int*)d_in[1];
  float* outf = (float*)d_out;  // fp32 output

  // d_out halves double as bf16 h-buffers (dead before fp32 heads overwrite):
  u16* regionA = (u16*)d_out;                     // h1
  u16* regionB = (u16*)d_out + (size_t)NN * 128;  // h0

  char* p = (char*)d_ws;
  auto alloc = [&](size_t bytes) -> char* {
    char* r = p; p += (bytes + 255) & ~(size_t)255; return r;
  };
  char* z0      = p;
  int*   cnt    = (int*)alloc(NN * 4);
  size_t zbytes = (size_t)(p - z0);
  int*   row_off= (int*)alloc((NN + 1) * 4);
  int*   bsum   = (int*)alloc(512);
  int*   boff   = (int*)alloc(512);
  int*   mode   = (int*)alloc(256);
  int*   fflag  = (int*)alloc(256);
  float* la     = (float*)alloc(NN * 4);
  float* asrcA  = (float*)alloc(NN * 4);
  float* adstA  = (float*)alloc(NN * 4);
  float* asrcB  = (float*)alloc(NN * 4);
  float* adstB  = (float*)alloc(NN * 4);
  int*   esrc   = (int*)alloc((size_t)EE * 4);
  u16*   eww    = (u16*)alloc((size_t)EE * 2);
  u16*   WT0    = (u16*)alloc(128 * 128 * 2);
  u16*   WT1    = (u16*)alloc(128 * 128 * 2);
  u16*   WTh    = (u16*)alloc(128 * 128 * 2);
  float* cvals  = (float*)alloc(16);
  u16*   vecc   = (u16*)alloc(9 * 256);
  u16*   xl     = (u16*)alloc((size_t)NN * 128 * 2);  // 25.6 MB

  // rank[e] aliases xl: dead until first k_gemm, consumed by k_place before that.
  int* rank = (int*)xl;  // 6.4 MB <= 25.6 MB

  size_t NEED = (size_t)(p - (char*)d_ws);  // ~38 MB
  if (ws_size < NEED) {
    k_fillf<<<(out_size + 255) / 256, 256, 0, stream>>>(outf, out_size, 0.125f);
    return;
  }

  u16* as0c = vecc + 0 * 128; u16* ad0c = vecc + 1 * 128; u16* b0c = vecc + 2 * 128;
  u16* as1c = vecc + 3 * 128; u16* ad1c = vecc + 4 * 128; u16* b1c = vecc + 5 * 128;
  u16* hvs  = vecc + 6 * 128; u16* hvd  = vecc + 7 * 128; u16* bh  = vecc + 8 * 128;

  // ---- detection ----
  k_fdetect<<<1, 64, 0, stream>>>((const u16*)d_in[0], fflag);
  k_detect<<<1, 64, 0, stream>>>(ei, mode);

  // ---- small vectors -> bf16 ws ----
  CvtPack pk;
  pk.d[0]  = {d_in[4],  as0c, 128};
  pk.d[1]  = {d_in[5],  ad0c, 128};
  pk.d[2]  = {d_in[8],  b0c,  128};
  pk.d[3]  = {d_in[10], as1c, 128};
  pk.d[4]  = {d_in[11], ad1c, 128};
  pk.d[5]  = {d_in[14], b1c,  128};
  pk.d[6]  = {d_in[16], hvs,      64};  // asm -> hvs[0:64)
  pk.d[7]  = {d_in[22], hvs + 64, 64};  // asl -> hvs[64:128)
  pk.d[8]  = {d_in[17], hvd,      64};  // adm
  pk.d[9]  = {d_in[23], hvd + 64, 64};  // adl
  pk.d[10] = {d_in[20], bh,       64};  // bm
  pk.d[11] = {d_in[24], bh + 64,  64};  // bl
  k_cvt_small<<<12, 64, 0, stream>>>(pk, fflag);

  const int nz = (int)(zbytes / 4);
  k_zero<<<(nz + 255) / 256, 256, 0, stream>>>((int*)z0, nz);

  const int Eblocks = (EE + 255) / 256;
  const int nchunks = (NN + 1023) / 1024;
  // ---- CSR build: 1 atomic/edge total (rank), then atomic-free placement ----
  k_rank<<<Eblocks, 256, 0, stream>>>(ei, mode, cnt, rank, EE);
  k_bsum<<<nchunks, 256, 0, stream>>>(cnt, bsum, NN);
  k_scanb<<<1, 128, 0, stream>>>(bsum, boff, nchunks);
  k_scan_chunk<<<nchunks, 256, 0, stream>>>(cnt, boff, row_off, NN, EE);
  k_place<<<Eblocks, 256, 0, stream>>>(ei, mode, d_in[2], fflag, row_off, rank, esrc, eww, EE);
  k_loop2<<<(NN + 255) / 256, 256, 0, stream>>>(row_off, eww, la, NN);
  k_tr<<<64, 256, 0, stream>>>(d_in[3],  fflag, WT0, 128);
  k_tr<<<64, 256, 0, stream>>>(d_in[9],  fflag, WT1, 128);
  k_tr<<<32, 256, 0, stream>>>(d_in[15], fflag, WTh, 64);             // Wm -> rows 0-63
  k_tr<<<32, 256, 0, stream>>>(d_in[21], fflag, WTh + 64 * 128, 64);  // Wl -> rows 64-127
  k_dots<<<3, 64, 0, stream>>>(d_in[7], d_in[6], d_in[13], d_in[12], d_in[19], d_in[18],
                               fflag, cvals);

  const int gblocks = (((NN + 15) / 16) + 3) / 4;
  const int eblocks = (int)(((size_t)NN * 64 + 255) / 256);

  // layer 0: x (fp32|bf16) -> xl -> h0(regionB)
  k_gemm<true, false><<<gblocks, 256, 0, stream>>>(d_in[0], fflag, WT0, as0c, ad0c,
                                                   xl, asrcA, adstA, nullptr, nullptr, NN);
  k_agg<<<eblocks, 256, 0, stream>>>(row_off, esrc, eww, asrcA, adstA, la,
                                     cvals + 0, xl, b0c, regionB, NN);
  // layer 1: h0 -> xl -> h1(regionA)
  k_gemm<false, false><<<gblocks, 256, 0, stream>>>(regionB, fflag, WT1, as1c, ad1c,
                                                    xl, asrcA, adstA, nullptr, nullptr, NN);
  k_agg<<<eblocks, 256, 0, stream>>>(row_off, esrc, eww, asrcA, adstA, la,
                                     cvals + 1, xl, b1c, regionA, NN);
  // heads: h1 -> xl[cols 0-63 mu | 64-127 logstd] -> fp32 mu/logstd (fused dual)
  k_gemm<false, true><<<gblocks, 256, 0, stream>>>(regionA, fflag, WTh, hvs, hvd,
                                                   xl, asrcA, adstA, asrcB, adstB, NN);
  k_aggh<<<eblocks, 256, 0, stream>>>(row_off, esrc, eww, asrcA, adstA, asrcB, adstB,
                                      la, cvals + 2, xl, bh, outf, NN);
}

// Round 4
// 565.351 us; speedup vs baseline: 1.5635x; 1.0927x over previous
//
#include <hip/hip_runtime.h>

#define NN 100000
#define EE 1600000

typedef __attribute__((ext_vector_type(8))) __bf16 bf16x8;
typedef __attribute__((ext_vector_type(4))) float f32x4;
typedef unsigned short u16;

__device__ __forceinline__ float bf2f(u16 v) {
  union { unsigned u; float f; } x; x.u = ((unsigned)v) << 16; return x.f;
}
__device__ __forceinline__ u16 f2bf(float f) {
  union { unsigned u; float f; } x; x.f = f;
  x.u += 0x7fffu + ((x.u >> 16) & 1u);
  return (u16)(x.u >> 16);
}
__device__ __forceinline__ float lo_f(unsigned u) {
  union { unsigned u; float f; } x; x.u = u << 16; return x.f;
}
__device__ __forceinline__ float hi_f(unsigned u) {
  union { unsigned u; float f; } x; x.u = u & 0xffff0000u; return x.f;
}
__device__ __forceinline__ float lrelu(float x) { return x > 0.f ? x : 0.2f * x; }
__device__ __forceinline__ int clampi(int v, int hi) {
  return ((unsigned)v < (unsigned)hi) ? v : 0;
}
// dtype-aware float load: fl=1 -> fp32 source, fl=0 -> bf16 source
__device__ __forceinline__ float ldf(const void* p, size_t i, int fl) {
  return fl ? ((const float*)p)[i] : bf2f(((const u16*)p)[i]);
}

// ---- per-wave inline dtype detection (replaces fflag/mode scratch) ----
// fp32-vs-bf16: interpret first 256 u16 of x as bf16; fp32 mantissa halves
// look like huge/NaN bf16 with overwhelming probability.
__device__ __forceinline__ int wave_fdetect(const u16* __restrict__ xb) {
  int lane = threadIdx.x & 63;
  int bad = 0;
#pragma unroll
  for (int j = 0; j < 4; ++j) {
    float a = fabsf(bf2f(xb[lane * 4 + j]));
    bad |= (!(a == a) || a > 1e6f) ? 1 : 0;
  }
  return (__ballot(bad) != 0ull) ? 1 : 0;
}
// int64-vs-int32 edge_index: odd 32-bit words of first 64 all zero -> int64.
__device__ __forceinline__ int wave_mdetect(const int* __restrict__ ei) {
  int lane = threadIdx.x & 63;
  int v = (lane < 32) ? ei[2 * lane + 1] : 0;
  return (__ballot(v != 0) == 0ull) ? 1 : 0;
}

// ---------- sentinel fill (ws too small diagnostic) ----------
__global__ void k_fillf(float* __restrict__ o, int n, float v) {
  int i = blockIdx.x * 256 + threadIdx.x;
  if (i < n) o[i] = v;
}

// ---------- fused setup: zero cnt + small-vec cvt + weight transpose + dots ----------
struct CvtDesc { const void* src; u16* dst; int n; };
struct SetupArgs {
  CvtDesc cvt[12];
  const void* W[4]; u16* WT[4]; int WM[4];
  const void* dw[3]; const void* da[3]; int dm[3];
  float* cvals;
  int* cnt;
  const u16* xb;
};
__global__ __launch_bounds__(256) void k_setup(SetupArgs a) {
  int b = blockIdx.x, t = threadIdx.x;
  const int ZB = (NN + 255) / 256;  // 391
  if (b < ZB) { int i = b * 256 + t; if (i < NN) a.cnt[i] = 0; return; }
  b -= ZB;
  if (b < 12) {  // small-vector conversions
    int fl = wave_fdetect(a.xb);
    const void* src = a.cvt[b].src; u16* dst = a.cvt[b].dst; int n = a.cvt[b].n;
    for (int i = t; i < n; i += 256)
      dst[i] = fl ? f2bf(((const float*)src)[i]) : ((const u16*)src)[i];
    return;
  }
  b -= 12;
  if (b < 192) {  // weight transposes: W0:64, W1:64, Wm:32, Wl:32 blocks
    int fl = wave_fdetect(a.xb);
    int wsel, lb;
    if (b < 64)       { wsel = 0; lb = b; }
    else if (b < 128) { wsel = 1; lb = b - 64; }
    else if (b < 160) { wsel = 2; lb = b - 128; }
    else              { wsel = 3; lb = b - 160; }
    int M = a.WM[wsel];
    int i = lb * 256 + t;
    if (i < 128 * M) {
      int k = i / M, m = i % M;
      a.WT[wsel][m * 128 + k] = f2bf(ldf(a.W[wsel], i, fl));
    }
    return;
  }
  b -= 192;
  if (b < 3) {  // c = dot(We[0,:], a_e) per layer
    if (t < 64) {
      int fl = wave_fdetect(a.xb);
      float s = 0.f; int m = a.dm[b];
      for (int j = t; j < m; j += 64) s += ldf(a.dw[b], j, fl) * ldf(a.da[b], j, fl);
      for (int off = 32; off; off >>= 1) s += __shfl_xor(s, off);
      if (t == 0) a.cvals[b] = s;
    }
    return;
  }
}

// ---------- scans (CSR row offsets) ----------
__global__ void k_bsum(const int* __restrict__ cnt, int* __restrict__ bsum, int n) {
  int b = blockIdx.x, t = threadIdx.x;
  int i0 = b * 1024 + t * 4;
  int s = 0;
#pragma unroll
  for (int j = 0; j < 4; ++j) { int i = i0 + j; if (i < n) s += cnt[i]; }
  for (int off = 32; off; off >>= 1) s += __shfl_xor(s, off);
  __shared__ int wt[4];
  int lane = t & 63, w = t >> 6;
  if (lane == 0) wt[w] = s;
  __syncthreads();
  if (t == 0) bsum[b] = wt[0] + wt[1] + wt[2] + wt[3];
}

__global__ void k_scanb(const int* __restrict__ bsum, int* __restrict__ boff, int nchunks) {
  int t = threadIdx.x;
  int lane = t & 63, w = t >> 6;
  int v = (t < nchunks) ? bsum[t] : 0;
  int sc = v;
  for (int off = 1; off < 64; off <<= 1) { int o = __shfl_up(sc, off); if (lane >= off) sc += o; }
  __shared__ int w0tot;
  if (w == 0 && lane == 63) w0tot = sc;
  __syncthreads();
  int incl = sc + (w ? w0tot : 0);
  if (t < nchunks) boff[t] = incl - v;
}

__global__ void k_scan_chunk(const int* __restrict__ cnt, const int* __restrict__ boff,
                             int* __restrict__ row_off, int n, int etot) {
  int b = blockIdx.x, t = threadIdx.x;
  int i0 = b * 1024 + t * 4;
  int v[4]; int s = 0;
#pragma unroll
  for (int j = 0; j < 4; ++j) { int i = i0 + j; v[j] = (i < n) ? cnt[i] : 0; s += v[j]; }
  int lane = t & 63, w = t >> 6;
  int sc = s;
  for (int off = 1; off < 64; off <<= 1) { int o = __shfl_up(sc, off); if (lane >= off) sc += o; }
  __shared__ int wt[4];
  if (lane == 63) wt[w] = sc;
  __syncthreads();
  int woff = 0;
  for (int k = 0; k < w; ++k) woff += wt[k];
  int ex = boff[b] + woff + sc - s;
#pragma unroll
  for (int j = 0; j < 4; ++j) { int i = i0 + j; if (i < n) row_off[i] = ex; ex += v[j]; }
  if (b == 0 && t == 0) row_off[n] = etot;
}

// ---------- GEMM body (shared): xl = A @ W + logit epilogues ----------
template<bool DUAL>
__device__ __forceinline__ void gemm_body(
    int bid, int fl, const void* __restrict__ Araw,
    const u16* __restrict__ WT,
    const u16* __restrict__ avs, const u16* __restrict__ avd,
    u16* __restrict__ xl,
    float* __restrict__ asrc, float* __restrict__ adst,
    float2* __restrict__ asAB, float* __restrict__ adstB, int n) {
  const int K = 128;
  int lane = threadIdx.x & 63;
  int wave = threadIdx.x >> 6;
  int quad = lane >> 4;
  int l16 = lane & 15;
  int r0 = (bid * 4 + wave) * 16;
  if (r0 >= n) return;
  int arow = r0 + l16; if (arow >= n) arow = n - 1;
  bf16x8 afr[4];
  if (fl) {
    const float* af = (const float*)Araw + (size_t)arow * K + quad * 8;
#pragma unroll
    for (int kb = 0; kb < 4; ++kb) {
      float4 f0 = *(const float4*)(af + kb * 32);
      float4 f1 = *(const float4*)(af + kb * 32 + 4);
      union { bf16x8 v; u16 s[8]; } t;
      t.s[0] = f2bf(f0.x); t.s[1] = f2bf(f0.y); t.s[2] = f2bf(f0.z); t.s[3] = f2bf(f0.w);
      t.s[4] = f2bf(f1.x); t.s[5] = f2bf(f1.y); t.s[6] = f2bf(f1.z); t.s[7] = f2bf(f1.w);
      afr[kb] = t.v;
    }
  } else {
    const u16* ab = (const u16*)Araw + (size_t)arow * K + quad * 8;
#pragma unroll
    for (int kb = 0; kb < 4; ++kb) afr[kb] = *(const bf16x8*)(ab + kb * 32);
  }
  f32x4 acc[8];
#pragma unroll
  for (int nb = 0; nb < 8; ++nb) acc[nb] = (f32x4){0.f, 0.f, 0.f, 0.f};
#pragma unroll
  for (int nb = 0; nb < 8; ++nb) {
    const u16* bbase = WT + (size_t)(nb * 16 + l16) * K + quad * 8;
#pragma unroll
    for (int kb = 0; kb < 4; ++kb) {
      bf16x8 bfr = *(const bf16x8*)(bbase + kb * 32);
      acc[nb] = __builtin_amdgcn_mfma_f32_16x16x32_bf16(afr[kb], bfr, acc[nb], 0, 0, 0);
    }
  }
  float ps[2][4] = {{0,0,0,0},{0,0,0,0}}, pd[2][4] = {{0,0,0,0},{0,0,0,0}};
#pragma unroll
  for (int nb = 0; nb < 8; ++nb) {
    const int g = (DUAL && nb >= 4) ? 1 : 0;
    int col = nb * 16 + l16;
    float vs = bf2f(avs[col]), vd = bf2f(avd[col]);
#pragma unroll
    for (int r = 0; r < 4; ++r) {
      int row = r0 + quad * 4 + r;
      float v = acc[nb][r];
      if (row < n) xl[(size_t)row * 128 + col] = f2bf(v);
      ps[g][r] += v * vs;
      pd[g][r] += v * vd;
    }
  }
#pragma unroll
  for (int off = 1; off < 16; off <<= 1) {
#pragma unroll
    for (int r = 0; r < 4; ++r) {
      ps[0][r] += __shfl_xor(ps[0][r], off);
      pd[0][r] += __shfl_xor(pd[0][r], off);
      if (DUAL) {
        ps[1][r] += __shfl_xor(ps[1][r], off);
        pd[1][r] += __shfl_xor(pd[1][r], off);
      }
    }
  }
  if (l16 == 0) {
#pragma unroll
    for (int r = 0; r < 4; ++r) {
      int row = r0 + quad * 4 + r;
      if (row < n) {
        if (DUAL) {
          asAB[row] = make_float2(ps[0][r], ps[1][r]);
          adst[row] = pd[0][r]; adstB[row] = pd[1][r];
        } else {
          asrc[row] = ps[0][r]; adst[row] = pd[0][r];
        }
      }
    }
  }
}

// ---------- MERGED: layer-0 GEMM (compute-heavy) + rank pass (atomic-bound) ----------
__global__ __launch_bounds__(256) void k_rkgemm(
    const int* __restrict__ ei, int* __restrict__ cnt, int* __restrict__ rank,
    const u16* __restrict__ xb, const void* __restrict__ Araw,
    const u16* __restrict__ WT, const u16* __restrict__ avs, const u16* __restrict__ avd,
    u16* __restrict__ xl, float* __restrict__ asrc, float* __restrict__ adst,
    int n, int gemmBlocks) {
  if ((int)blockIdx.x < gemmBlocks) {
    int fl = wave_fdetect(xb);
    gemm_body<false>(blockIdx.x, fl, Araw, WT, avs, avd, xl, asrc, adst,
                     nullptr, nullptr, n);
  } else {
    int m_ = wave_mdetect(ei);
    int e = ((int)blockIdx.x - gemmBlocks) * 256 + threadIdx.x;
    if (e >= EE) return;
    int d = m_ ? ei[2 * (size_t)(EE + e)] : ei[EE + e];
    d = clampi(d, NN);
    rank[e] = atomicAdd(&cnt[d], 1);
  }
}

// ---------- standalone GEMM (bf16 A) ----------
template<bool DUAL>
__global__ __launch_bounds__(256) void k_gemm(
    const u16* __restrict__ A, const u16* __restrict__ WT,
    const u16* __restrict__ avs, const u16* __restrict__ avd,
    u16* __restrict__ xl, float* __restrict__ asrc, float* __restrict__ adst,
    float2* __restrict__ asAB, float* __restrict__ adstB, int n) {
  gemm_body<DUAL>(blockIdx.x, 0, A, WT, avs, avd, xl, asrc, adst, asAB, adstB, n);
}

// ---------- CSR placement (NO atomics): packed edge record {src, bf16 w} ----------
__global__ void k_place(const int* __restrict__ ei, const void* __restrict__ ew,
                        const u16* __restrict__ xb,
                        const int* __restrict__ row_off, const int* __restrict__ rank,
                        int2* __restrict__ edges) {
  int m_ = wave_mdetect(ei);
  int fl = wave_fdetect(xb);
  int e = blockIdx.x * 256 + threadIdx.x;
  if (e >= EE) return;
  int s = m_ ? ei[2 * (size_t)e] : ei[e];
  int d = m_ ? ei[2 * (size_t)(EE + e)] : ei[EE + e];
  s = clampi(s, NN);
  d = clampi(d, NN);
  int p = row_off[d] + rank[e];
  if (p >= 0 && p < EE) edges[p] = make_int2(s, (int)f2bf(ldf(ew, e, fl)));
}

// ---------- self-loop attr = mean incoming weight, from CSR ----------
__global__ void k_loop2(const int* __restrict__ row_off, const int2* __restrict__ edges,
                        float* __restrict__ la, int n) {
  int i = blockIdx.x * 256 + threadIdx.x;
  if (i >= n) return;
  int b = row_off[i], e = row_off[i + 1];
  float s = 0.f;
  for (int j = b; j < e; ++j) s += bf2f((u16)(edges[j].y & 0xffff));
  la[i] = (e > b) ? s / (float)(e - b) : 0.f;
}

// ---------- FUSED softmax+aggregation (layers): fixed reference m = self logit ----------
// Coefficients are reference-invariant; logits are O(10) so exp(al-aL) is safe.
// No per-chunk cross-lane reductions: den accumulated per-lane, reduced once.
__global__ __launch_bounds__(256) void k_agg(
    const int* __restrict__ row_off, const int2* __restrict__ edges,
    const float* __restrict__ asrc, const float* __restrict__ adst,
    const float* __restrict__ la, const float* __restrict__ cptr,
    const u16* __restrict__ xl, const u16* __restrict__ bias,
    u16* __restrict__ out, int n) {
  __shared__ float lp[4][64];
  __shared__ int lsv[4][64];
  int wid = (blockIdx.x * blockDim.x + threadIdx.x) >> 6;
  if (wid >= n) return;
  int w = threadIdx.x >> 6;
  int d = __builtin_amdgcn_readfirstlane(wid);
  int lane = threadIdx.x & 63;
  float c = cptr[0];
  float ad = adst[d];
  float aL = lrelu(asrc[d] + ad + c * la[d]);
  float lsum = 0.f;
  unsigned su = *(const unsigned*)(xl + (size_t)d * 128 + 2 * lane);
  float A0 = lo_f(su), A1 = hi_f(su);  // self term: weight exp(aL-aL)=1
  int beg = row_off[d], end = row_off[d + 1];
  for (int base = beg; base < end; base += 64) {
    int i = base + lane;
    bool v = i < end;
    int2 ev = v ? edges[i] : make_int2(0, 0);
    int s = ev.x;
    float e = 0.f;
    if (v) {
      float al = lrelu(asrc[s] + ad + c * bf2f((u16)(ev.y & 0xffff)));
      e = __expf(al - aL);
    }
    lsum += e;
    lp[w][lane] = e; lsv[w][lane] = s;
    int cnt = end - base; if (cnt > 64) cnt = 64;
    float B0 = 0.f, B1 = 0.f, C0 = 0.f, C1 = 0.f, D0 = 0.f, D1 = 0.f;
    int j = 0;
    for (; j + 4 <= cnt; j += 4) {
      float p0 = lp[w][j + 0]; int s0 = lsv[w][j + 0];
      float p1 = lp[w][j + 1]; int s1 = lsv[w][j + 1];
      float p2 = lp[w][j + 2]; int s2 = lsv[w][j + 2];
      float p3 = lp[w][j + 3]; int s3 = lsv[w][j + 3];
      unsigned u0 = *(const unsigned*)(xl + (size_t)s0 * 128 + 2 * lane);
      unsigned u1 = *(const unsigned*)(xl + (size_t)s1 * 128 + 2 * lane);
      unsigned u2 = *(const unsigned*)(xl + (size_t)s2 * 128 + 2 * lane);
      unsigned u3 = *(const unsigned*)(xl + (size_t)s3 * 128 + 2 * lane);
      A0 = fmaf(p0, lo_f(u0), A0); A1 = fmaf(p0, hi_f(u0), A1);
      B0 = fmaf(p1, lo_f(u1), B0); B1 = fmaf(p1, hi_f(u1), B1);
      C0 = fmaf(p2, lo_f(u2), C0); C1 = fmaf(p2, hi_f(u2), C1);
      D0 = fmaf(p3, lo_f(u3), D0); D1 = fmaf(p3, hi_f(u3), D1);
    }
    for (; j < cnt; ++j) {
      float p0 = lp[w][j]; int s0 = lsv[w][j];
      unsigned u0 = *(const unsigned*)(xl + (size_t)s0 * 128 + 2 * lane);
      A0 = fmaf(p0, lo_f(u0), A0); A1 = fmaf(p0, hi_f(u0), A1);
    }
    A0 += B0 + C0 + D0; A1 += B1 + C1 + D1;
  }
#pragma unroll
  for (int off = 32; off; off >>= 1) lsum += __shfl_xor(lsum, off);
  float inv = 1.f / (lsum + 1.f);
  float o0 = fmaxf(fmaf(A0, inv, bf2f(bias[2 * lane])), 0.f);
  float o1 = fmaxf(fmaf(A1, inv, bf2f(bias[2 * lane + 1])), 0.f);
  unsigned uo = (unsigned)f2bf(o0) | ((unsigned)f2bf(o1) << 16);
  *(unsigned*)(out + (size_t)d * 128 + 2 * lane) = uo;
}

// ---------- FUSED dual-head: lanes 0-31 mu (edge-attr), 32-63 logstd ----------
__global__ __launch_bounds__(256) void k_aggh(
    const int* __restrict__ row_off, const int2* __restrict__ edges,
    const float2* __restrict__ asAB, const float* __restrict__ adA,
    const float* __restrict__ adB,
    const float* __restrict__ la, const float* __restrict__ cptr,
    const u16* __restrict__ xl, const u16* __restrict__ bias,
    float* __restrict__ outf, int n) {
  __shared__ float lpA[4][64];
  __shared__ float lpB[4][64];
  __shared__ int lsv[4][64];
  int wid = (blockIdx.x * blockDim.x + threadIdx.x) >> 6;
  if (wid >= n) return;
  int w = threadIdx.x >> 6;
  int d = __builtin_amdgcn_readfirstlane(wid);
  int lane = threadIdx.x & 63;
  bool isMu = lane < 32;
  float c = cptr[0];
  float adAd = adA[d], adBd = adB[d];
  float2 abd = asAB[d];
  float aLA = lrelu(abd.x + adAd + c * la[d]);
  float aLB = lrelu(abd.y + adBd);
  float lsA = 0.f, lsB = 0.f;
  unsigned su = *(const unsigned*)(xl + (size_t)d * 128 + 2 * lane);
  float A0 = lo_f(su), A1 = hi_f(su);  // self weight 1 in each lane's stream
  int beg = row_off[d], end = row_off[d + 1];
  for (int base = beg; base < end; base += 64) {
    int i = base + lane;
    bool v = i < end;
    int2 ev = v ? edges[i] : make_int2(0, 0);
    int s = ev.x;
    float eA = 0.f, eB = 0.f;
    if (v) {
      float2 ab = asAB[s];
      eA = __expf(lrelu(ab.x + adAd + c * bf2f((u16)(ev.y & 0xffff))) - aLA);
      eB = __expf(lrelu(ab.y + adBd) - aLB);
    }
    lsA += eA; lsB += eB;
    lpA[w][lane] = eA; lpB[w][lane] = eB; lsv[w][lane] = s;
    const float* lpp = isMu ? lpA[w] : lpB[w];
    int cnt = end - base; if (cnt > 64) cnt = 64;
    float B0 = 0.f, B1 = 0.f, C0 = 0.f, C1 = 0.f, D0 = 0.f, D1 = 0.f;
    int j = 0;
    for (; j + 4 <= cnt; j += 4) {
      float p0 = lpp[j + 0]; int s0 = lsv[w][j + 0];
      float p1 = lpp[j + 1]; int s1 = lsv[w][j + 1];
      float p2 = lpp[j + 2]; int s2 = lsv[w][j + 2];
      float p3 = lpp[j + 3]; int s3 = lsv[w][j + 3];
      unsigned u0 = *(const unsigned*)(xl + (size_t)s0 * 128 + 2 * lane);
      unsigned u1 = *(const unsigned*)(xl + (size_t)s1 * 128 + 2 * lane);
      unsigned u2 = *(const unsigned*)(xl + (size_t)s2 * 128 + 2 * lane);
      unsigned u3 = *(const unsigned*)(xl + (size_t)s3 * 128 + 2 * lane);
      A0 = fmaf(p0, lo_f(u0), A0); A1 = fmaf(p0, hi_f(u0), A1);
      B0 = fmaf(p1, lo_f(u1), B0); B1 = fmaf(p1, hi_f(u1), B1);
      C0 = fmaf(p2, lo_f(u2), C0); C1 = fmaf(p2, hi_f(u2), C1);
      D0 = fmaf(p3, lo_f(u3), D0); D1 = fmaf(p3, hi_f(u3), D1);
    }
    for (; j < cnt; ++j) {
      float p0 = lpp[j]; int s0 = lsv[w][j];
      unsigned u0 = *(const unsigned*)(xl + (size_t)s0 * 128 + 2 * lane);
      A0 = fmaf(p0, lo_f(u0), A0); A1 = fmaf(p0, hi_f(u0), A1);
    }
    A0 += B0 + C0 + D0; A1 += B1 + C1 + D1;
  }
#pragma unroll
  for (int off = 32; off; off >>= 1) {
    lsA += __shfl_xor(lsA, off);
    lsB += __shfl_xor(lsB, off);
  }
  float inv = 1.f / ((isMu ? lsA : lsB) + 1.f);
  int col0 = 2 * lane;
  float o0 = fmaf(A0, inv, bf2f(bias[col0]));
  float o1 = fmaf(A1, inv, bf2f(bias[col0 + 1]));
  float* ob = isMu ? (outf + (size_t)d * 64 + col0)
                   : (outf + (size_t)NN * 64 + (size_t)d * 64 + (col0 - 64));
  ob[0] = o0; ob[1] = o1;
}

extern "C" void kernel_launch(void* const* d_in, const int* in_sizes, int n_in,
                              void* d_out, int out_size, void* d_ws, size_t ws_size,
                              hipStream_t stream) {
  (void)in_sizes; (void)n_in;
  const int* ei = (const int*)d_in[1];
  const u16* xb = (const u16*)d_in[0];
  float* outf = (float*)d_out;  // fp32 output

  // d_out regions double as scratch (dead before fp32 heads overwrite):
  // rank lives in regionA area (first 6.4MB), consumed by k_place before
  // anything writes d_out; h0 -> regionB (agg L0), h1 -> regionA (agg L1).
  u16* regionA = (u16*)d_out;                     // h1
  u16* regionB = (u16*)d_out + (size_t)NN * 128;  // h0
  int* rank = (int*)d_out;                        // 6.4 MB, dead until agg L1

  char* p = (char*)d_ws;
  auto alloc = [&](size_t bytes) -> char* {
    char* r = p; p += (bytes + 255) & ~(size_t)255; return r;
  };
  int*   cnt    = (int*)alloc(NN * 4);
  int*   row_off= (int*)alloc((NN + 1) * 4);
  int*   bsum   = (int*)alloc(512);
  int*   boff   = (int*)alloc(512);
  float* la     = (float*)alloc(NN * 4);
  float* asrcA  = (float*)alloc(NN * 4);
  float* adstA  = (float*)alloc(NN * 4);
  float* adstB  = (float*)alloc(NN * 4);
  float2* asAB  = (float2*)alloc((size_t)NN * 8);
  int2*  edges  = (int2*)alloc((size_t)EE * 8);   // packed {src, bf16 w}
  u16*   WT0    = (u16*)alloc(128 * 128 * 2);
  u16*   WT1    = (u16*)alloc(128 * 128 * 2);
  u16*   WTh    = (u16*)alloc(128 * 128 * 2);
  float* cvals  = (float*)alloc(16);
  u16*   vecc   = (u16*)alloc(9 * 256);
  u16*   xl     = (u16*)alloc((size_t)NN * 128 * 2);  // 25.6 MB

  size_t NEED = (size_t)(p - (char*)d_ws);  // ~41.7 MB (<= 42.2 proven)
  if (ws_size < NEED) {
    k_fillf<<<(out_size + 255) / 256, 256, 0, stream>>>(outf, out_size, 0.125f);
    return;
  }

  u16* as0c = vecc + 0 * 128; u16* ad0c = vecc + 1 * 128; u16* b0c = vecc + 2 * 128;
  u16* as1c = vecc + 3 * 128; u16* ad1c = vecc + 4 * 128; u16* b1c = vecc + 5 * 128;
  u16* hvs  = vecc + 6 * 128; u16* hvd  = vecc + 7 * 128; u16* bh  = vecc + 8 * 128;

  // ---- fused setup ----
  SetupArgs sa;
  sa.cvt[0]  = {d_in[4],  as0c, 128};
  sa.cvt[1]  = {d_in[5],  ad0c, 128};
  sa.cvt[2]  = {d_in[8],  b0c,  128};
  sa.cvt[3]  = {d_in[10], as1c, 128};
  sa.cvt[4]  = {d_in[11], ad1c, 128};
  sa.cvt[5]  = {d_in[14], b1c,  128};
  sa.cvt[6]  = {d_in[16], hvs,      64};  // asm
  sa.cvt[7]  = {d_in[22], hvs + 64, 64};  // asl
  sa.cvt[8]  = {d_in[17], hvd,      64};  // adm
  sa.cvt[9]  = {d_in[23], hvd + 64, 64};  // adl
  sa.cvt[10] = {d_in[20], bh,       64};  // bm
  sa.cvt[11] = {d_in[24], bh + 64,  64};  // bl
  sa.W[0] = d_in[3];  sa.WT[0] = WT0;            sa.WM[0] = 128;
  sa.W[1] = d_in[9];  sa.WT[1] = WT1;            sa.WM[1] = 128;
  sa.W[2] = d_in[15]; sa.WT[2] = WTh;            sa.WM[2] = 64;  // Wm -> rows 0-63
  sa.W[3] = d_in[21]; sa.WT[3] = WTh + 64 * 128; sa.WM[3] = 64;  // Wl -> rows 64-127
  sa.dw[0] = d_in[7];  sa.da[0] = d_in[6];  sa.dm[0] = 128;
  sa.dw[1] = d_in[13]; sa.da[1] = d_in[12]; sa.dm[1] = 128;
  sa.dw[2] = d_in[19]; sa.da[2] = d_in[18]; sa.dm[2] = 64;
  sa.cvals = cvals; sa.cnt = cnt; sa.xb = xb;
  const int ZB = (NN + 255) / 256;
  k_setup<<<ZB + 12 + 192 + 3, 256, 0, stream>>>(sa);

  const int Eblocks = (EE + 255) / 256;
  const int nchunks = (NN + 1023) / 1024;
  const int gblocks = (((NN + 15) / 16) + 3) / 4;
  const int eblocks = (int)(((size_t)NN * 64 + 255) / 256);

  // ---- layer-0 GEMM co-resident with rank pass (independent work) ----
  k_rkgemm<<<gblocks + Eblocks, 256, 0, stream>>>(ei, cnt, rank, xb, d_in[0],
                                                  WT0, as0c, ad0c, xl, asrcA, adstA,
                                                  NN, gblocks);
  // ---- CSR offsets + placement ----
  k_bsum<<<nchunks, 256, 0, stream>>>(cnt, bsum, NN);
  k_scanb<<<1, 128, 0, stream>>>(bsum, boff, nchunks);
  k_scan_chunk<<<nchunks, 256, 0, stream>>>(cnt, boff, row_off, NN, EE);
  k_place<<<Eblocks, 256, 0, stream>>>(ei, d_in[2], xb, row_off, rank, edges);
  k_loop2<<<(NN + 255) / 256, 256, 0, stream>>>(row_off, edges, la, NN);

  // ---- layer 0 aggregation: xl -> h0(regionB) ----
  k_agg<<<eblocks, 256, 0, stream>>>(row_off, edges, asrcA, adstA, la,
                                     cvals + 0, xl, b0c, regionB, NN);
  // ---- layer 1 ----
  k_gemm<false><<<gblocks, 256, 0, stream>>>(regionB, WT1, as1c, ad1c,
                                             xl, asrcA, adstA, nullptr, nullptr, NN);
  k_agg<<<eblocks, 256, 0, stream>>>(row_off, edges, asrcA, adstA, la,
                                     cvals + 1, xl, b1c, regionA, NN);
  // ---- heads: packed dual logits, fused dual aggregation ----
  k_gemm<true><<<gblocks, 256, 0, stream>>>(regionA, WTh, hvs, hvd,
                                            xl, nullptr, adstA, asAB, adstB, NN);
  k_aggh<<<eblocks, 256, 0, stream>>>(row_off, edges, asAB, adstA, adstB,
                                      la, cvals + 2, xl, bh, outf, NN);
}

// Round 5
// 536.813 us; speedup vs baseline: 1.6467x; 1.0532x over previous
//
#include <hip/hip_runtime.h>

#define NN 100000
#define EE 1600000
#define NBK 782          // coarse buckets = ceil(NN/128)
#define NBKP 784
#define NBLK 391         // edge blocks = ceil(EE/4096)
#define NBLKP 392

typedef __attribute__((ext_vector_type(8))) __bf16 bf16x8;
typedef __attribute__((ext_vector_type(4))) float f32x4;
typedef unsigned short u16;

__device__ __forceinline__ float bf2f(u16 v) {
  union { unsigned u; float f; } x; x.u = ((unsigned)v) << 16; return x.f;
}
__device__ __forceinline__ u16 f2bf(float f) {
  union { unsigned u; float f; } x; x.f = f;
  x.u += 0x7fffu + ((x.u >> 16) & 1u);
  return (u16)(x.u >> 16);
}
__device__ __forceinline__ float lo_f(unsigned u) {
  union { unsigned u; float f; } x; x.u = u << 16; return x.f;
}
__device__ __forceinline__ float hi_f(unsigned u) {
  union { unsigned u; float f; } x; x.u = u & 0xffff0000u; return x.f;
}
__device__ __forceinline__ float lrelu(float x) { return x > 0.f ? x : 0.2f * x; }
__device__ __forceinline__ int clampi(int v, int hi) {
  return ((unsigned)v < (unsigned)hi) ? v : 0;
}
// dtype-aware float load: fl=1 -> fp32 source, fl=0 -> bf16 source
__device__ __forceinline__ float ldf(const void* p, size_t i, int fl) {
  return fl ? ((const float*)p)[i] : bf2f(((const u16*)p)[i]);
}

// ---- per-wave inline dtype detection ----
__device__ __forceinline__ int wave_fdetect(const u16* __restrict__ xb) {
  int lane = threadIdx.x & 63;
  int bad = 0;
#pragma unroll
  for (int j = 0; j < 4; ++j) {
    float a = fabsf(bf2f(xb[lane * 4 + j]));
    bad |= (!(a == a) || a > 1e6f) ? 1 : 0;
  }
  return (__ballot(bad) != 0ull) ? 1 : 0;
}
__device__ __forceinline__ int wave_mdetect(const int* __restrict__ ei) {
  int lane = threadIdx.x & 63;
  int v = (lane < 32) ? ei[2 * lane + 1] : 0;
  return (__ballot(v != 0) == 0ull) ? 1 : 0;
}

// ---------- sentinel fill ----------
__global__ void k_fillf(float* __restrict__ o, int n, float v) {
  int i = blockIdx.x * 256 + threadIdx.x;
  if (i < n) o[i] = v;
}

// ---------- fused setup: small-vec cvt + weight transpose + dots ----------
struct CvtDesc { const void* src; u16* dst; int n; };
struct SetupArgs {
  CvtDesc cvt[12];
  const void* W[4]; u16* WT[4]; int WM[4];
  const void* dw[3]; const void* da[3]; int dm[3];
  float* cvals;
  const u16* xb;
};
__global__ __launch_bounds__(256) void k_setup(SetupArgs a) {
  int b = blockIdx.x, t = threadIdx.x;
  if (b < 12) {  // small-vector conversions
    int fl = wave_fdetect(a.xb);
    const void* src = a.cvt[b].src; u16* dst = a.cvt[b].dst; int n = a.cvt[b].n;
    for (int i = t; i < n; i += 256)
      dst[i] = fl ? f2bf(((const float*)src)[i]) : ((const u16*)src)[i];
    return;
  }
  b -= 12;
  if (b < 192) {  // weight transposes: W0:64, W1:64, Wm:32, Wl:32 blocks
    int fl = wave_fdetect(a.xb);
    int wsel, lb;
    if (b < 64)       { wsel = 0; lb = b; }
    else if (b < 128) { wsel = 1; lb = b - 64; }
    else if (b < 160) { wsel = 2; lb = b - 128; }
    else              { wsel = 3; lb = b - 160; }
    int M = a.WM[wsel];
    int i = lb * 256 + t;
    if (i < 128 * M) {
      int k = i / M, m = i % M;
      a.WT[wsel][m * 128 + k] = f2bf(ldf(a.W[wsel], i, fl));
    }
    return;
  }
  b -= 192;
  if (b < 3) {  // c = dot(We[0,:], a_e)
    if (t < 64) {
      int fl = wave_fdetect(a.xb);
      float s = 0.f; int m = a.dm[b];
      for (int j = t; j < m; j += 64) s += ldf(a.dw[b], j, fl) * ldf(a.da[b], j, fl);
      for (int off = 32; off; off >>= 1) s += __shfl_xor(s, off);
      if (t == 0) a.cvals[b] = s;
    }
    return;
  }
}

// ---------- CSR build, NO global atomics: coarse histogram ----------
__global__ __launch_bounds__(256) void k_ehist(const int* __restrict__ ei,
                                               int* __restrict__ histM) {
  __shared__ int h[NBKP];
  int blk = blockIdx.x, t = threadIdx.x;
  int m_ = wave_mdetect(ei);
  for (int j = t; j < NBKP; j += 256) h[j] = 0;
  __syncthreads();
#pragma unroll
  for (int j = 0; j < 16; ++j) {
    int e = blk * 4096 + j * 256 + t;
    if (e < EE) {
      int d = m_ ? ei[2 * (size_t)(EE + e)] : ei[EE + e];
      d = clampi(d, NN);
      atomicAdd(&h[d >> 7], 1);
    }
  }
  __syncthreads();
  for (int j = t; j < NBKP; j += 256) histM[j * NBLKP + blk] = h[j];
}

// ---------- per-bucket exclusive prefix over blocks (in-place) + bucket totals ----------
__global__ __launch_bounds__(512) void k_scanA(int* __restrict__ histM,
                                               int* __restrict__ binTot) {
  int b = blockIdx.x, t = threadIdx.x;
  int v = (t < NBLK) ? histM[b * NBLKP + t] : 0;
  int lane = t & 63, w = t >> 6;
  int sc = v;
  for (int off = 1; off < 64; off <<= 1) {
    int o = __shfl_up(sc, off); if (lane >= off) sc += o;
  }
  __shared__ int wt[8];
  if (lane == 63) wt[w] = sc;
  __syncthreads();
  int add = 0;
  for (int k = 0; k < w; ++k) add += wt[k];
  int excl = sc - v + add;
  if (t < NBLK) histM[b * NBLKP + t] = excl;
  if (t == 511) binTot[b] = excl;  // v=0 here -> excl = total
}

// ---------- exclusive scan of bucket totals -> bucketBase ----------
__global__ __launch_bounds__(256) void k_scanB(const int* __restrict__ binTot,
                                               int* __restrict__ bucketBase,
                                               int* __restrict__ row_off) {
  int t = threadIdx.x;
  int v[4]; int s = 0;
#pragma unroll
  for (int j = 0; j < 4; ++j) {
    int idx = t * 4 + j;
    v[j] = (idx < NBK) ? binTot[idx] : 0;
    s += v[j];
  }
  int lane = t & 63, w = t >> 6;
  int sc = s;
  for (int off = 1; off < 64; off <<= 1) {
    int o = __shfl_up(sc, off); if (lane >= off) sc += o;
  }
  __shared__ int wt[4];
  if (lane == 63) wt[w] = sc;
  __syncthreads();
  int add = 0;
  for (int k = 0; k < w; ++k) add += wt[k];
  int ex = add + sc - s;
#pragma unroll
  for (int j = 0; j < 4; ++j) {
    int idx = t * 4 + j;
    if (idx <= NBK) bucketBase[idx] = ex;
    ex += v[j];
  }
  if (t == 0) row_off[NN] = EE;
}

// ---------- scatter into coarse buckets (LDS ranks, no global atomics) ----------
__global__ __launch_bounds__(256) void k_escatter(
    const int* __restrict__ ei, const void* __restrict__ ew,
    const u16* __restrict__ xb, const int* __restrict__ histM,
    const int* __restrict__ bucketBase, int2* __restrict__ stage) {
  __shared__ int lbase[NBKP];
  __shared__ int cur[NBKP];
  int blk = blockIdx.x, t = threadIdx.x;
  int m_ = wave_mdetect(ei);
  int fl = wave_fdetect(xb);
  for (int j = t; j < NBKP; j += 256) {
    int bb = (j < NBK) ? (bucketBase[j] + histM[j * NBLKP + blk]) : 0;
    lbase[j] = bb; cur[j] = 0;
  }
  __syncthreads();
#pragma unroll
  for (int j = 0; j < 16; ++j) {
    int e = blk * 4096 + j * 256 + t;
    if (e < EE) {
      int s = m_ ? ei[2 * (size_t)e] : ei[e];
      int d = m_ ? ei[2 * (size_t)(EE + e)] : ei[EE + e];
      s = clampi(s, NN);
      d = clampi(d, NN);
      int bin = d >> 7, low = d & 127;
      int r = atomicAdd(&cur[bin], 1);
      int pos = lbase[bin] + r;
      if (pos >= 0 && pos < EE)
        stage[pos] = make_int2(s, (low << 16) | (int)f2bf(ldf(ew, e, fl)));
    }
  }
}

// ---------- per-bucket counting sort by low7 -> final CSR + row_off + la ----------
__global__ __launch_bounds__(256) void k_bucket(
    const int2* __restrict__ stage, const int* __restrict__ bucketBase,
    int2* __restrict__ edges, int* __restrict__ row_off, float* __restrict__ la) {
  __shared__ int hist[128];
  __shared__ float wsum[128];
  __shared__ int pref[128];
  __shared__ int cur[128];
  int b = blockIdx.x, t = threadIdx.x;
  int base = bucketBase[b], n = bucketBase[b + 1] - base;
  if (t < 128) { hist[t] = 0; wsum[t] = 0.f; cur[t] = 0; }
  __syncthreads();
  for (int i = t; i < n; i += 256) {
    int2 it = stage[base + i];
    int bin = (it.y >> 16) & 127;
    atomicAdd(&hist[bin], 1);
    atomicAdd(&wsum[bin], bf2f((u16)(it.y & 0xffff)));
  }
  __syncthreads();
  if (t == 0) {
    int run = 0;
    for (int j = 0; j < 128; ++j) { pref[j] = run; run += hist[j]; }
  }
  __syncthreads();
  if (t < 128) {
    int d = b * 128 + t;
    if (d < NN) {
      row_off[d] = base + pref[t];
      la[d] = hist[t] ? wsum[t] / (float)hist[t] : 0.f;
    }
  }
  for (int i = t; i < n; i += 256) {
    int2 it = stage[base + i];
    int bin = (it.y >> 16) & 127;
    int r = atomicAdd(&cur[bin], 1);
    edges[base + pref[bin] + r] = it;
  }
}

// ---------- GEMM body: xl = A @ W + logit epilogues ----------
template<bool DUAL>
__device__ __forceinline__ void gemm_body(
    int bid, int fl, const void* __restrict__ Araw,
    const u16* __restrict__ WT,
    const u16* __restrict__ avs, const u16* __restrict__ avd,
    u16* __restrict__ xl,
    float* __restrict__ asrc, float* __restrict__ adst,
    float2* __restrict__ asAB, float* __restrict__ adstB, int n) {
  const int K = 128;
  int lane = threadIdx.x & 63;
  int wave = threadIdx.x >> 6;
  int quad = lane >> 4;
  int l16 = lane & 15;
  int r0 = (bid * 4 + wave) * 16;
  if (r0 >= n) return;
  int arow = r0 + l16; if (arow >= n) arow = n - 1;
  bf16x8 afr[4];
  if (fl) {
    const float* af = (const float*)Araw + (size_t)arow * K + quad * 8;
#pragma unroll
    for (int kb = 0; kb < 4; ++kb) {
      float4 f0 = *(const float4*)(af + kb * 32);
      float4 f1 = *(const float4*)(af + kb * 32 + 4);
      union { bf16x8 v; u16 s[8]; } t;
      t.s[0] = f2bf(f0.x); t.s[1] = f2bf(f0.y); t.s[2] = f2bf(f0.z); t.s[3] = f2bf(f0.w);
      t.s[4] = f2bf(f1.x); t.s[5] = f2bf(f1.y); t.s[6] = f2bf(f1.z); t.s[7] = f2bf(f1.w);
      afr[kb] = t.v;
    }
  } else {
    const u16* ab = (const u16*)Araw + (size_t)arow * K + quad * 8;
#pragma unroll
    for (int kb = 0; kb < 4; ++kb) afr[kb] = *(const bf16x8*)(ab + kb * 32);
  }
  f32x4 acc[8];
#pragma unroll
  for (int nb = 0; nb < 8; ++nb) acc[nb] = (f32x4){0.f, 0.f, 0.f, 0.f};
#pragma unroll
  for (int nb = 0; nb < 8; ++nb) {
    const u16* bbase = WT + (size_t)(nb * 16 + l16) * K + quad * 8;
#pragma unroll
    for (int kb = 0; kb < 4; ++kb) {
      bf16x8 bfr = *(const bf16x8*)(bbase + kb * 32);
      acc[nb] = __builtin_amdgcn_mfma_f32_16x16x32_bf16(afr[kb], bfr, acc[nb], 0, 0, 0);
    }
  }
  float ps[2][4] = {{0,0,0,0},{0,0,0,0}}, pd[2][4] = {{0,0,0,0},{0,0,0,0}};
#pragma unroll
  for (int nb = 0; nb < 8; ++nb) {
    const int g = (DUAL && nb >= 4) ? 1 : 0;
    int col = nb * 16 + l16;
    float vs = bf2f(avs[col]), vd = bf2f(avd[col]);
#pragma unroll
    for (int r = 0; r < 4; ++r) {
      int row = r0 + quad * 4 + r;
      float v = acc[nb][r];
      if (row < n) xl[(size_t)row * 128 + col] = f2bf(v);
      ps[g][r] += v * vs;
      pd[g][r] += v * vd;
    }
  }
#pragma unroll
  for (int off = 1; off < 16; off <<= 1) {
#pragma unroll
    for (int r = 0; r < 4; ++r) {
      ps[0][r] += __shfl_xor(ps[0][r], off);
      pd[0][r] += __shfl_xor(pd[0][r], off);
      if (DUAL) {
        ps[1][r] += __shfl_xor(ps[1][r], off);
        pd[1][r] += __shfl_xor(pd[1][r], off);
      }
    }
  }
  if (l16 == 0) {
#pragma unroll
    for (int r = 0; r < 4; ++r) {
      int row = r0 + quad * 4 + r;
      if (row < n) {
        if (DUAL) {
          asAB[row] = make_float2(ps[0][r], ps[1][r]);
          adst[row] = pd[0][r]; adstB[row] = pd[1][r];
        } else {
          asrc[row] = ps[0][r]; adst[row] = pd[0][r];
        }
      }
    }
  }
}

// ---------- layer-0 GEMM (runtime fp32|bf16 A) ----------
__global__ __launch_bounds__(256) void k_gemm0(
    const u16* __restrict__ xb, const void* __restrict__ Araw,
    const u16* __restrict__ WT, const u16* __restrict__ avs, const u16* __restrict__ avd,
    u16* __restrict__ xl, float* __restrict__ asrc, float* __restrict__ adst, int n) {
  int fl = wave_fdetect(xb);
  gemm_body<false>(blockIdx.x, fl, Araw, WT, avs, avd, xl, asrc, adst,
                   nullptr, nullptr, n);
}

// ---------- standalone GEMM (bf16 A) ----------
template<bool DUAL>
__global__ __launch_bounds__(256) void k_gemm(
    const u16* __restrict__ A, const u16* __restrict__ WT,
    const u16* __restrict__ avs, const u16* __restrict__ avd,
    u16* __restrict__ xl, float* __restrict__ asrc, float* __restrict__ adst,
    float2* __restrict__ asAB, float* __restrict__ adstB, int n) {
  gemm_body<DUAL>(blockIdx.x, 0, A, WT, avs, avd, xl, asrc, adst, asAB, adstB, n);
}

// ---------- FUSED softmax+aggregation (layers): fixed reference m = self logit ----------
__global__ __launch_bounds__(256) void k_agg(
    const int* __restrict__ row_off, const int2* __restrict__ edges,
    const float* __restrict__ asrc, const float* __restrict__ adst,
    const float* __restrict__ la, const float* __restrict__ cptr,
    const u16* __restrict__ xl, const u16* __restrict__ bias,
    u16* __restrict__ out, int n) {
  __shared__ float lp[4][64];
  __shared__ int lsv[4][64];
  int wid = (blockIdx.x * blockDim.x + threadIdx.x) >> 6;
  if (wid >= n) return;
  int w = threadIdx.x >> 6;
  int d = __builtin_amdgcn_readfirstlane(wid);
  int lane = threadIdx.x & 63;
  float c = cptr[0];
  float ad = adst[d];
  float aL = lrelu(asrc[d] + ad + c * la[d]);
  float lsum = 0.f;
  unsigned su = *(const unsigned*)(xl + (size_t)d * 128 + 2 * lane);
  float A0 = lo_f(su), A1 = hi_f(su);
  int beg = row_off[d], end = row_off[d + 1];
  for (int base = beg; base < end; base += 64) {
    int i = base + lane;
    bool v = i < end;
    int2 ev = v ? edges[i] : make_int2(0, 0);
    int s = ev.x;
    float e = 0.f;
    if (v) {
      float al = lrelu(asrc[s] + ad + c * bf2f((u16)(ev.y & 0xffff)));
      e = __expf(al - aL);
    }
    lsum += e;
    lp[w][lane] = e; lsv[w][lane] = s;
    int cnt = end - base; if (cnt > 64) cnt = 64;
    float B0 = 0.f, B1 = 0.f, C0 = 0.f, C1 = 0.f, D0 = 0.f, D1 = 0.f;
    int j = 0;
    for (; j + 4 <= cnt; j += 4) {
      float p0 = lp[w][j + 0]; int s0 = lsv[w][j + 0];
      float p1 = lp[w][j + 1]; int s1 = lsv[w][j + 1];
      float p2 = lp[w][j + 2]; int s2 = lsv[w][j + 2];
      float p3 = lp[w][j + 3]; int s3 = lsv[w][j + 3];
      unsigned u0 = *(const unsigned*)(xl + (size_t)s0 * 128 + 2 * lane);
      unsigned u1 = *(const unsigned*)(xl + (size_t)s1 * 128 + 2 * lane);
      unsigned u2 = *(const unsigned*)(xl + (size_t)s2 * 128 + 2 * lane);
      unsigned u3 = *(const unsigned*)(xl + (size_t)s3 * 128 + 2 * lane);
      A0 = fmaf(p0, lo_f(u0), A0); A1 = fmaf(p0, hi_f(u0), A1);
      B0 = fmaf(p1, lo_f(u1), B0); B1 = fmaf(p1, hi_f(u1), B1);
      C0 = fmaf(p2, lo_f(u2), C0); C1 = fmaf(p2, hi_f(u2), C1);
      D0 = fmaf(p3, lo_f(u3), D0); D1 = fmaf(p3, hi_f(u3), D1);
    }
    for (; j < cnt; ++j) {
      float p0 = lp[w][j]; int s0 = lsv[w][j];
      unsigned u0 = *(const unsigned*)(xl + (size_t)s0 * 128 + 2 * lane);
      A0 = fmaf(p0, lo_f(u0), A0); A1 = fmaf(p0, hi_f(u0), A1);
    }
    A0 += B0 + C0 + D0; A1 += B1 + C1 + D1;
  }
#pragma unroll
  for (int off = 32; off; off >>= 1) lsum += __shfl_xor(lsum, off);
  float inv = 1.f / (lsum + 1.f);
  float o0 = fmaxf(fmaf(A0, inv, bf2f(bias[2 * lane])), 0.f);
  float o1 = fmaxf(fmaf(A1, inv, bf2f(bias[2 * lane + 1])), 0.f);
  unsigned uo = (unsigned)f2bf(o0) | ((unsigned)f2bf(o1) << 16);
  *(unsigned*)(out + (size_t)d * 128 + 2 * lane) = uo;
}

// ---------- FUSED dual-head: lanes 0-31 mu (edge-attr), 32-63 logstd ----------
__global__ __launch_bounds__(256) void k_aggh(
    const int* __restrict__ row_off, const int2* __restrict__ edges,
    const float2* __restrict__ asAB, const float* __restrict__ adA,
    const float* __restrict__ adB,
    const float* __restrict__ la, const float* __restrict__ cptr,
    const u16* __restrict__ xl, const u16* __restrict__ bias,
    float* __restrict__ outf, int n) {
  __shared__ float lpA[4][64];
  __shared__ float lpB[4][64];
  __shared__ int lsv[4][64];
  int wid = (blockIdx.x * blockDim.x + threadIdx.x) >> 6;
  if (wid >= n) return;
  int w = threadIdx.x >> 6;
  int d = __builtin_amdgcn_readfirstlane(wid);
  int lane = threadIdx.x & 63;
  bool isMu = lane < 32;
  float c = cptr[0];
  float adAd = adA[d], adBd = adB[d];
  float2 abd = asAB[d];
  float aLA = lrelu(abd.x + adAd + c * la[d]);
  float aLB = lrelu(abd.y + adBd);
  float lsA = 0.f, lsB = 0.f;
  unsigned su = *(const unsigned*)(xl + (size_t)d * 128 + 2 * lane);
  float A0 = lo_f(su), A1 = hi_f(su);
  int beg = row_off[d], end = row_off[d + 1];
  for (int base = beg; base < end; base += 64) {
    int i = base + lane;
    bool v = i < end;
    int2 ev = v ? edges[i] : make_int2(0, 0);
    int s = ev.x;
    float eA = 0.f, eB = 0.f;
    if (v) {
      float2 ab = asAB[s];
      eA = __expf(lrelu(ab.x + adAd + c * bf2f((u16)(ev.y & 0xffff))) - aLA);
      eB = __expf(lrelu(ab.y + adBd) - aLB);
    }
    lsA += eA; lsB += eB;
    lpA[w][lane] = eA; lpB[w][lane] = eB; lsv[w][lane] = s;
    const float* lpp = isMu ? lpA[w] : lpB[w];
    int cnt = end - base; if (cnt > 64) cnt = 64;
    float B0 = 0.f, B1 = 0.f, C0 = 0.f, C1 = 0.f, D0 = 0.f, D1 = 0.f;
    int j = 0;
    for (; j + 4 <= cnt; j += 4) {
      float p0 = lpp[j + 0]; int s0 = lsv[w][j + 0];
      float p1 = lpp[j + 1]; int s1 = lsv[w][j + 1];
      float p2 = lpp[j + 2]; int s2 = lsv[w][j + 2];
      float p3 = lpp[j + 3]; int s3 = lsv[w][j + 3];
      unsigned u0 = *(const unsigned*)(xl + (size_t)s0 * 128 + 2 * lane);
      unsigned u1 = *(const unsigned*)(xl + (size_t)s1 * 128 + 2 * lane);
      unsigned u2 = *(const unsigned*)(xl + (size_t)s2 * 128 + 2 * lane);
      unsigned u3 = *(const unsigned*)(xl + (size_t)s3 * 128 + 2 * lane);
      A0 = fmaf(p0, lo_f(u0), A0); A1 = fmaf(p0, hi_f(u0), A1);
      B0 = fmaf(p1, lo_f(u1), B0); B1 = fmaf(p1, hi_f(u1), B1);
      C0 = fmaf(p2, lo_f(u2), C0); C1 = fmaf(p2, hi_f(u2), C1);
      D0 = fmaf(p3, lo_f(u3), D0); D1 = fmaf(p3, hi_f(u3), D1);
    }
    for (; j < cnt; ++j) {
      float p0 = lpp[j]; int s0 = lsv[w][j];
      unsigned u0 = *(const unsigned*)(xl + (size_t)s0 * 128 + 2 * lane);
      A0 = fmaf(p0, lo_f(u0), A0); A1 = fmaf(p0, hi_f(u0), A1);
    }
    A0 += B0 + C0 + D0; A1 += B1 + C1 + D1;
  }
#pragma unroll
  for (int off = 32; off; off >>= 1) {
    lsA += __shfl_xor(lsA, off);
    lsB += __shfl_xor(lsB, off);
  }
  float inv = 1.f / ((isMu ? lsA : lsB) + 1.f);
  int col0 = 2 * lane;
  float o0 = fmaf(A0, inv, bf2f(bias[col0]));
  float o1 = fmaf(A1, inv, bf2f(bias[col0 + 1]));
  float* ob = isMu ? (outf + (size_t)d * 64 + col0)
                   : (outf + (size_t)NN * 64 + (size_t)d * 64 + (col0 - 64));
  ob[0] = o0; ob[1] = o1;
}

extern "C" void kernel_launch(void* const* d_in, const int* in_sizes, int n_in,
                              void* d_out, int out_size, void* d_ws, size_t ws_size,
                              hipStream_t stream) {
  (void)in_sizes; (void)n_in;
  const int* ei = (const int*)d_in[1];
  const u16* xb = (const u16*)d_in[0];
  float* outf = (float*)d_out;  // fp32 output

  // d_out scratch: histM (1.23MB) at offset 0 — dead before agg L1 writes h1.
  // regionA = h1 (agg L1 output), regionB = h0 (agg L0 output).
  u16* regionA = (u16*)d_out;                     // h1
  u16* regionB = (u16*)d_out + (size_t)NN * 128;  // h0
  int* histM = (int*)d_out;                       // [NBKP][NBLKP] = 1.23 MB

  char* p = (char*)d_ws;
  auto alloc = [&](size_t bytes) -> char* {
    char* r = p; p += (bytes + 255) & ~(size_t)255; return r;
  };
  int*   row_off   = (int*)alloc((NN + 1) * 4);
  int*   binTot    = (int*)alloc(NBKP * 4);
  int*   bucketBase= (int*)alloc((NBKP + 2) * 4);
  float* la        = (float*)alloc(NN * 4);
  float* asrcA     = (float*)alloc(NN * 4);
  float* adstA     = (float*)alloc(NN * 4);
  float* adstB     = (float*)alloc(NN * 4);
  float2* asAB     = (float2*)alloc((size_t)NN * 8);
  int2*  edges     = (int2*)alloc((size_t)EE * 8);   // final CSR {src, low7|w}
  u16*   WT0       = (u16*)alloc(128 * 128 * 2);
  u16*   WT1       = (u16*)alloc(128 * 128 * 2);
  u16*   WTh       = (u16*)alloc(128 * 128 * 2);
  float* cvals     = (float*)alloc(16);
  u16*   vecc      = (u16*)alloc(9 * 256);
  u16*   xl        = (u16*)alloc((size_t)NN * 128 * 2);  // 25.6 MB

  // stage aliases xl: consumed by k_bucket BEFORE k_gemm0 writes xl.
  int2* stage = (int2*)xl;  // 12.8 MB <= 25.6 MB

  size_t NEED = (size_t)(p - (char*)d_ws);  // ~41.3 MB (< 41.7 proven in R4)
  if (ws_size < NEED) {
    k_fillf<<<(out_size + 255) / 256, 256, 0, stream>>>(outf, out_size, 0.125f);
    return;
  }

  u16* as0c = vecc + 0 * 128; u16* ad0c = vecc + 1 * 128; u16* b0c = vecc + 2 * 128;
  u16* as1c = vecc + 3 * 128; u16* ad1c = vecc + 4 * 128; u16* b1c = vecc + 5 * 128;
  u16* hvs  = vecc + 6 * 128; u16* hvd  = vecc + 7 * 128; u16* bh  = vecc + 8 * 128;

  // ---- fused setup ----
  SetupArgs sa;
  sa.cvt[0]  = {d_in[4],  as0c, 128};
  sa.cvt[1]  = {d_in[5],  ad0c, 128};
  sa.cvt[2]  = {d_in[8],  b0c,  128};
  sa.cvt[3]  = {d_in[10], as1c, 128};
  sa.cvt[4]  = {d_in[11], ad1c, 128};
  sa.cvt[5]  = {d_in[14], b1c,  128};
  sa.cvt[6]  = {d_in[16], hvs,      64};  // asm
  sa.cvt[7]  = {d_in[22], hvs + 64, 64};  // asl
  sa.cvt[8]  = {d_in[17], hvd,      64};  // adm
  sa.cvt[9]  = {d_in[23], hvd + 64, 64};  // adl
  sa.cvt[10] = {d_in[20], bh,       64};  // bm
  sa.cvt[11] = {d_in[24], bh + 64,  64};  // bl
  sa.W[0] = d_in[3];  sa.WT[0] = WT0;            sa.WM[0] = 128;
  sa.W[1] = d_in[9];  sa.WT[1] = WT1;            sa.WM[1] = 128;
  sa.W[2] = d_in[15]; sa.WT[2] = WTh;            sa.WM[2] = 64;  // Wm -> rows 0-63
  sa.W[3] = d_in[21]; sa.WT[3] = WTh + 64 * 128; sa.WM[3] = 64;  // Wl -> rows 64-127
  sa.dw[0] = d_in[7];  sa.da[0] = d_in[6];  sa.dm[0] = 128;
  sa.dw[1] = d_in[13]; sa.da[1] = d_in[12]; sa.dm[1] = 128;
  sa.dw[2] = d_in[19]; sa.da[2] = d_in[18]; sa.dm[2] = 64;
  sa.cvals = cvals; sa.xb = xb;
  k_setup<<<12 + 192 + 3, 256, 0, stream>>>(sa);

  const int gblocks = (((NN + 15) / 16) + 3) / 4;
  const int eblocks = (int)(((size_t)NN * 64 + 255) / 256);

  // ---- CSR build (zero global atomics) ----
  k_ehist<<<NBLK, 256, 0, stream>>>(ei, histM);
  k_scanA<<<NBK, 512, 0, stream>>>(histM, binTot);
  k_scanB<<<1, 256, 0, stream>>>(binTot, bucketBase, row_off);
  k_escatter<<<NBLK, 256, 0, stream>>>(ei, d_in[2], xb, histM, bucketBase, stage);
  k_bucket<<<NBK, 256, 0, stream>>>(stage, bucketBase, edges, row_off, la);

  // ---- layer 0: x -> xl (overwrites stage, now dead) -> h0(regionB) ----
  k_gemm0<<<gblocks, 256, 0, stream>>>(xb, d_in[0], WT0, as0c, ad0c,
                                       xl, asrcA, adstA, NN);
  k_agg<<<eblocks, 256, 0, stream>>>(row_off, edges, asrcA, adstA, la,
                                     cvals + 0, xl, b0c, regionB, NN);
  // ---- layer 1 ----
  k_gemm<false><<<gblocks, 256, 0, stream>>>(regionB, WT1, as1c, ad1c,
                                             xl, asrcA, adstA, nullptr, nullptr, NN);
  k_agg<<<eblocks, 256, 0, stream>>>(row_off, edges, asrcA, adstA, la,
                                     cvals + 1, xl, b1c, regionA, NN);
  // ---- heads ----
  k_gemm<true><<<gblocks, 256, 0, stream>>>(regionA, WTh, hvs, hvd,
                                            xl, nullptr, adstA, asAB, adstB, NN);
  k_aggh<<<eblocks, 256, 0, stream>>>(row_off, edges, asAB, adstA, adstB,
                                      la, cvals + 2, xl, bh, outf, NN);
}

// Round 7
// 526.238 us; speedup vs baseline: 1.6798x; 1.0201x over previous
//
#include <hip/hip_runtime.h>

#define NN 100000
#define EE 1600000
#define NBK 782          // coarse buckets = ceil(NN/128)
#define NBKP 784
#define NBLK 391         // edge blocks = ceil(EE/4096)
#define NBLKP 392

typedef __attribute__((ext_vector_type(8))) __bf16 bf16x8;
typedef __attribute__((ext_vector_type(4))) float f32x4;
typedef unsigned short u16;

__device__ __forceinline__ float bf2f(u16 v) {
  union { unsigned u; float f; } x; x.u = ((unsigned)v) << 16; return x.f;
}
__device__ __forceinline__ u16 f2bf(float f) {
  union { unsigned u; float f; } x; x.f = f;
  x.u += 0x7fffu + ((x.u >> 16) & 1u);
  return (u16)(x.u >> 16);
}
__device__ __forceinline__ float lo_f(unsigned u) {
  union { unsigned u; float f; } x; x.u = u << 16; return x.f;
}
__device__ __forceinline__ float hi_f(unsigned u) {
  union { unsigned u; float f; } x; x.u = u & 0xffff0000u; return x.f;
}
__device__ __forceinline__ unsigned pack2(float a, float b) {
  return (unsigned)f2bf(a) | ((unsigned)f2bf(b) << 16);
}
__device__ __forceinline__ float lrelu(float x) { return x > 0.f ? x : 0.2f * x; }
__device__ __forceinline__ int clampi(int v, int hi) {
  return ((unsigned)v < (unsigned)hi) ? v : 0;
}
// dtype-aware float load: fl=1 -> fp32 source, fl=0 -> bf16 source
__device__ __forceinline__ float ldf(const void* p, size_t i, int fl) {
  return fl ? ((const float*)p)[i] : bf2f(((const u16*)p)[i]);
}

// ---- per-wave inline dtype detection ----
__device__ __forceinline__ int wave_fdetect(const u16* __restrict__ xb) {
  int lane = threadIdx.x & 63;
  int bad = 0;
#pragma unroll
  for (int j = 0; j < 4; ++j) {
    float a = fabsf(bf2f(xb[lane * 4 + j]));
    bad |= (!(a == a) || a > 1e6f) ? 1 : 0;
  }
  return (__ballot(bad) != 0ull) ? 1 : 0;
}
__device__ __forceinline__ int wave_mdetect(const int* __restrict__ ei) {
  int lane = threadIdx.x & 63;
  int v = (lane < 32) ? ei[2 * lane + 1] : 0;
  return (__ballot(v != 0) == 0ull) ? 1 : 0;
}

// ---------- sentinel fill ----------
__global__ void k_fillf(float* __restrict__ o, int n, float v) {
  int i = blockIdx.x * 256 + threadIdx.x;
  if (i < n) o[i] = v;
}

// ---------- fused setup: small-vec cvt + weight transpose + dots ----------
struct CvtDesc { const void* src; u16* dst; int n; };
struct SetupArgs {
  CvtDesc cvt[12];
  const void* W[4]; u16* WT[4]; int WM[4];
  const void* dw[3]; const void* da[3]; int dm[3];
  float* cvals;
  const u16* xb;
};
__global__ __launch_bounds__(256) void k_setup(SetupArgs a) {
  int b = blockIdx.x, t = threadIdx.x;
  if (b < 12) {  // small-vector conversions
    int fl = wave_fdetect(a.xb);
    const void* src = a.cvt[b].src; u16* dst = a.cvt[b].dst; int n = a.cvt[b].n;
    for (int i = t; i < n; i += 256)
      dst[i] = fl ? f2bf(((const float*)src)[i]) : ((const u16*)src)[i];
    return;
  }
  b -= 12;
  if (b < 192) {  // weight transposes: W0:64, W1:64, Wm:32, Wl:32 blocks
    int fl = wave_fdetect(a.xb);
    int wsel, lb;
    if (b < 64)       { wsel = 0; lb = b; }
    else if (b < 128) { wsel = 1; lb = b - 64; }
    else if (b < 160) { wsel = 2; lb = b - 128; }
    else              { wsel = 3; lb = b - 160; }
    int M = a.WM[wsel];
    int i = lb * 256 + t;
    if (i < 128 * M) {
      int k = i / M, m = i % M;
      a.WT[wsel][m * 128 + k] = f2bf(ldf(a.W[wsel], i, fl));
    }
    return;
  }
  b -= 192;
  if (b < 3) {  // c = dot(We[0,:], a_e)
    if (t < 64) {
      int fl = wave_fdetect(a.xb);
      float s = 0.f; int m = a.dm[b];
      for (int j = t; j < m; j += 64) s += ldf(a.dw[b], j, fl) * ldf(a.da[b], j, fl);
      for (int off = 32; off; off >>= 1) s += __shfl_xor(s, off);
      if (t == 0) a.cvals[b] = s;
    }
    return;
  }
}

// ---------- CSR build, NO global atomics: coarse histogram ----------
__global__ __launch_bounds__(256) void k_ehist(const int* __restrict__ ei,
                                               int* __restrict__ histM) {
  __shared__ int h[NBKP];
  int blk = blockIdx.x, t = threadIdx.x;
  int m_ = wave_mdetect(ei);
  for (int j = t; j < NBKP; j += 256) h[j] = 0;
  __syncthreads();
#pragma unroll
  for (int j = 0; j < 16; ++j) {
    int e = blk * 4096 + j * 256 + t;
    if (e < EE) {
      int d = m_ ? ei[2 * (size_t)(EE + e)] : ei[EE + e];
      d = clampi(d, NN);
      atomicAdd(&h[d >> 7], 1);
    }
  }
  __syncthreads();
  for (int j = t; j < NBKP; j += 256) histM[j * NBLKP + blk] = h[j];
}

// ---------- per-bucket exclusive prefix over blocks (in-place) + bucket totals ----------
__global__ __launch_bounds__(512) void k_scanA(int* __restrict__ histM,
                                               int* __restrict__ binTot) {
  int b = blockIdx.x, t = threadIdx.x;
  int v = (t < NBLK) ? histM[b * NBLKP + t] : 0;
  int lane = t & 63, w = t >> 6;
  int sc = v;
  for (int off = 1; off < 64; off <<= 1) {
    int o = __shfl_up(sc, off); if (lane >= off) sc += o;
  }
  __shared__ int wt[8];
  if (lane == 63) wt[w] = sc;
  __syncthreads();
  int add = 0;
  for (int k = 0; k < w; ++k) add += wt[k];
  int excl = sc - v + add;
  if (t < NBLK) histM[b * NBLKP + t] = excl;
  if (t == 511) binTot[b] = excl;  // v=0 here -> excl = total
}

// ---------- exclusive scan of bucket totals -> bucketBase ----------
__global__ __launch_bounds__(256) void k_scanB(const int* __restrict__ binTot,
                                               int* __restrict__ bucketBase,
                                               int* __restrict__ row_off) {
  int t = threadIdx.x;
  int v[4]; int s = 0;
#pragma unroll
  for (int j = 0; j < 4; ++j) {
    int idx = t * 4 + j;
    v[j] = (idx < NBK) ? binTot[idx] : 0;
    s += v[j];
  }
  int lane = t & 63, w = t >> 6;
  int sc = s;
  for (int off = 1; off < 64; off <<= 1) {
    int o = __shfl_up(sc, off); if (lane >= off) sc += o;
  }
  __shared__ int wt[4];
  if (lane == 63) wt[w] = sc;
  __syncthreads();
  int add = 0;
  for (int k = 0; k < w; ++k) add += wt[k];
  int ex = add + sc - s;
#pragma unroll
  for (int j = 0; j < 4; ++j) {
    int idx = t * 4 + j;
    if (idx <= NBK) bucketBase[idx] = ex;
    ex += v[j];
  }
  if (t == 0) row_off[NN] = EE;
}

// ---------- scatter into coarse buckets (LDS ranks, no global atomics) ----------
__global__ __launch_bounds__(256) void k_escatter(
    const int* __restrict__ ei, const void* __restrict__ ew,
    const u16* __restrict__ xb, const int* __restrict__ histM,
    const int* __restrict__ bucketBase, int2* __restrict__ stage) {
  __shared__ int lbase[NBKP];
  __shared__ int cur[NBKP];
  int blk = blockIdx.x, t = threadIdx.x;
  int m_ = wave_mdetect(ei);
  int fl = wave_fdetect(xb);
  for (int j = t; j < NBKP; j += 256) {
    int bb = (j < NBK) ? (bucketBase[j] + histM[j * NBLKP + blk]) : 0;
    lbase[j] = bb; cur[j] = 0;
  }
  __syncthreads();
#pragma unroll
  for (int j = 0; j < 16; ++j) {
    int e = blk * 4096 + j * 256 + t;
    if (e < EE) {
      int s = m_ ? ei[2 * (size_t)e] : ei[e];
      int d = m_ ? ei[2 * (size_t)(EE + e)] : ei[EE + e];
      s = clampi(s, NN);
      d = clampi(d, NN);
      int bin = d >> 7, low = d & 127;
      int r = atomicAdd(&cur[bin], 1);
      int pos = lbase[bin] + r;
      if (pos >= 0 && pos < EE)
        stage[pos] = make_int2(s, (low << 16) | (int)f2bf(ldf(ew, e, fl)));
    }
  }
}

// ---------- per-bucket counting sort by low7 -> final CSR + row_off + la ----------
__global__ __launch_bounds__(256) void k_bucket(
    const int2* __restrict__ stage, const int* __restrict__ bucketBase,
    int2* __restrict__ edges, int* __restrict__ row_off, float* __restrict__ la) {
  __shared__ int hist[128];
  __shared__ float wsum[128];
  __shared__ int pref[128];
  __shared__ int cur[128];
  int b = blockIdx.x, t = threadIdx.x;
  int base = bucketBase[b], n = bucketBase[b + 1] - base;
  if (t < 128) { hist[t] = 0; wsum[t] = 0.f; cur[t] = 0; }
  __syncthreads();
  for (int i = t; i < n; i += 256) {
    int2 it = stage[base + i];
    int bin = (it.y >> 16) & 127;
    atomicAdd(&hist[bin], 1);
    atomicAdd(&wsum[bin], bf2f((u16)(it.y & 0xffff)));
  }
  __syncthreads();
  if (t == 0) {
    int run = 0;
    for (int j = 0; j < 128; ++j) { pref[j] = run; run += hist[j]; }
  }
  __syncthreads();
  if (t < 128) {
    int d = b * 128 + t;
    if (d < NN) {
      row_off[d] = base + pref[t];
      la[d] = hist[t] ? wsum[t] / (float)hist[t] : 0.f;
    }
  }
  for (int i = t; i < n; i += 256) {
    int2 it = stage[base + i];
    int bin = (it.y >> 16) & 127;
    int r = atomicAdd(&cur[bin], 1);
    edges[base + pref[bin] + r] = it;
  }
}

// ---------- GEMM body: xl = A @ W + logit epilogues ----------
template<bool DUAL>
__device__ __forceinline__ void gemm_body(
    int bid, int fl, const void* __restrict__ Araw,
    const u16* __restrict__ WT,
    const u16* __restrict__ avs, const u16* __restrict__ avd,
    u16* __restrict__ xl,
    float* __restrict__ asrc, float* __restrict__ adst,
    float2* __restrict__ asAB, float* __restrict__ adstB, int n) {
  const int K = 128;
  int lane = threadIdx.x & 63;
  int wave = threadIdx.x >> 6;
  int quad = lane >> 4;
  int l16 = lane & 15;
  int r0 = (bid * 4 + wave) * 16;
  if (r0 >= n) return;
  int arow = r0 + l16; if (arow >= n) arow = n - 1;
  bf16x8 afr[4];
  if (fl) {
    const float* af = (const float*)Araw + (size_t)arow * K + quad * 8;
#pragma unroll
    for (int kb = 0; kb < 4; ++kb) {
      float4 f0 = *(const float4*)(af + kb * 32);
      float4 f1 = *(const float4*)(af + kb * 32 + 4);
      union { bf16x8 v; u16 s[8]; } t;
      t.s[0] = f2bf(f0.x); t.s[1] = f2bf(f0.y); t.s[2] = f2bf(f0.z); t.s[3] = f2bf(f0.w);
      t.s[4] = f2bf(f1.x); t.s[5] = f2bf(f1.y); t.s[6] = f2bf(f1.z); t.s[7] = f2bf(f1.w);
      afr[kb] = t.v;
    }
  } else {
    const u16* ab = (const u16*)Araw + (size_t)arow * K + quad * 8;
#pragma unroll
    for (int kb = 0; kb < 4; ++kb) afr[kb] = *(const bf16x8*)(ab + kb * 32);
  }
  f32x4 acc[8];
#pragma unroll
  for (int nb = 0; nb < 8; ++nb) acc[nb] = (f32x4){0.f, 0.f, 0.f, 0.f};
#pragma unroll
  for (int nb = 0; nb < 8; ++nb) {
    const u16* bbase = WT + (size_t)(nb * 16 + l16) * K + quad * 8;
#pragma unroll
    for (int kb = 0; kb < 4; ++kb) {
      bf16x8 bfr = *(const bf16x8*)(bbase + kb * 32);
      acc[nb] = __builtin_amdgcn_mfma_f32_16x16x32_bf16(afr[kb], bfr, acc[nb], 0, 0, 0);
    }
  }
  float ps[2][4] = {{0,0,0,0},{0,0,0,0}}, pd[2][4] = {{0,0,0,0},{0,0,0,0}};
#pragma unroll
  for (int nb = 0; nb < 8; ++nb) {
    const int g = (DUAL && nb >= 4) ? 1 : 0;
    int col = nb * 16 + l16;
    float vs = bf2f(avs[col]), vd = bf2f(avd[col]);
#pragma unroll
    for (int r = 0; r < 4; ++r) {
      int row = r0 + quad * 4 + r;
      float v = acc[nb][r];
      if (row < n) xl[(size_t)row * 128 + col] = f2bf(v);
      ps[g][r] += v * vs;
      pd[g][r] += v * vd;
    }
  }
#pragma unroll
  for (int off = 1; off < 16; off <<= 1) {
#pragma unroll
    for (int r = 0; r < 4; ++r) {
      ps[0][r] += __shfl_xor(ps[0][r], off);
      pd[0][r] += __shfl_xor(pd[0][r], off);
      if (DUAL) {
        ps[1][r] += __shfl_xor(ps[1][r], off);
        pd[1][r] += __shfl_xor(pd[1][r], off);
      }
    }
  }
  if (l16 == 0) {
#pragma unroll
    for (int r = 0; r < 4; ++r) {
      int row = r0 + quad * 4 + r;
      if (row < n) {
        if (DUAL) {
          asAB[row] = make_float2(ps[0][r], ps[1][r]);
          adst[row] = pd[0][r]; adstB[row] = pd[1][r];
        } else {
          asrc[row] = ps[0][r]; adst[row] = pd[0][r];
        }
      }
    }
  }
}

// ---------- layer-0 GEMM (runtime fp32|bf16 A) ----------
__global__ __launch_bounds__(256) void k_gemm0(
    const u16* __restrict__ xb, const void* __restrict__ Araw,
    const u16* __restrict__ WT, const u16* __restrict__ avs, const u16* __restrict__ avd,
    u16* __restrict__ xl, float* __restrict__ asrc, float* __restrict__ adst, int n) {
  int fl = wave_fdetect(xb);
  gemm_body<false>(blockIdx.x, fl, Araw, WT, avs, avd, xl, asrc, adst,
                   nullptr, nullptr, n);
}

// ---------- standalone GEMM (bf16 A) ----------
template<bool DUAL>
__global__ __launch_bounds__(256) void k_gemm(
    const u16* __restrict__ A, const u16* __restrict__ WT,
    const u16* __restrict__ avs, const u16* __restrict__ avd,
    u16* __restrict__ xl, float* __restrict__ asrc, float* __restrict__ adst,
    float2* __restrict__ asAB, float* __restrict__ adstB, int n) {
  gemm_body<DUAL>(blockIdx.x, 0, A, WT, avs, avd, xl, asrc, adst, asAB, adstB, n);
}

// ---------- FUSED softmax+aggregation, 16 lanes/node, int4 gathers ----------
// Fixed reference m = self logit (coefficients reference-invariant; logits O(10)).
// Lane l owns features [8l, 8l+8): gather = one global_load_dwordx4 per edge.
__global__ __launch_bounds__(256) void k_agg(
    const int* __restrict__ row_off, const int2* __restrict__ edges,
    const float* __restrict__ asrc, const float* __restrict__ adst,
    const float* __restrict__ la, const float* __restrict__ cptr,
    const u16* __restrict__ xl, const u16* __restrict__ bias,
    u16* __restrict__ out, int n) {
  __shared__ float lp[16][16];
  __shared__ int lsv[16][16];
  int tid = blockIdx.x * 256 + threadIdx.x;
  int d = tid >> 4;
  if (d >= n) return;
  int l = threadIdx.x & 15;
  int grp = threadIdx.x >> 4;
  float c = cptr[0];
  float ad = adst[d];
  float aL = lrelu(asrc[d] + ad + c * la[d]);
  float lsum = 0.f;
  int4 su = *(const int4*)(xl + (size_t)d * 128 + l * 8);
  float A0 = lo_f(su.x), A1 = hi_f(su.x), A2 = lo_f(su.y), A3 = hi_f(su.y);
  float A4 = lo_f(su.z), A5 = hi_f(su.z), A6 = lo_f(su.w), A7 = hi_f(su.w);
  float B0 = 0.f, B1 = 0.f, B2 = 0.f, B3 = 0.f, B4 = 0.f, B5 = 0.f, B6 = 0.f, B7 = 0.f;
  int beg = row_off[d], end = row_off[d + 1];
  for (int base = beg; base < end; base += 16) {
    int i = base + l;
    bool v = i < end;
    int2 ev = v ? edges[i] : make_int2(0, 0);
    float e = 0.f;
    if (v) e = __expf(lrelu(asrc[ev.x] + ad + c * bf2f((u16)(ev.y & 0xffff))) - aL);
    lsum += e;
    lp[grp][l] = e; lsv[grp][l] = ev.x;
    int cnt = end - base; if (cnt > 16) cnt = 16;
    int j = 0;
    for (; j + 2 <= cnt; j += 2) {
      float p0 = lp[grp][j];     int s0 = lsv[grp][j];
      float p1 = lp[grp][j + 1]; int s1 = lsv[grp][j + 1];
      int4 u0 = *(const int4*)(xl + (size_t)s0 * 128 + l * 8);
      int4 u1 = *(const int4*)(xl + (size_t)s1 * 128 + l * 8);
      A0 = fmaf(p0, lo_f(u0.x), A0); A1 = fmaf(p0, hi_f(u0.x), A1);
      A2 = fmaf(p0, lo_f(u0.y), A2); A3 = fmaf(p0, hi_f(u0.y), A3);
      A4 = fmaf(p0, lo_f(u0.z), A4); A5 = fmaf(p0, hi_f(u0.z), A5);
      A6 = fmaf(p0, lo_f(u0.w), A6); A7 = fmaf(p0, hi_f(u0.w), A7);
      B0 = fmaf(p1, lo_f(u1.x), B0); B1 = fmaf(p1, hi_f(u1.x), B1);
      B2 = fmaf(p1, lo_f(u1.y), B2); B3 = fmaf(p1, hi_f(u1.y), B3);
      B4 = fmaf(p1, lo_f(u1.z), B4); B5 = fmaf(p1, hi_f(u1.z), B5);
      B6 = fmaf(p1, lo_f(u1.w), B6); B7 = fmaf(p1, hi_f(u1.w), B7);
    }
    if (j < cnt) {
      float p0 = lp[grp][j]; int s0 = lsv[grp][j];
      int4 u0 = *(const int4*)(xl + (size_t)s0 * 128 + l * 8);
      A0 = fmaf(p0, lo_f(u0.x), A0); A1 = fmaf(p0, hi_f(u0.x), A1);
      A2 = fmaf(p0, lo_f(u0.y), A2); A3 = fmaf(p0, hi_f(u0.y), A3);
      A4 = fmaf(p0, lo_f(u0.z), A4); A5 = fmaf(p0, hi_f(u0.z), A5);
      A6 = fmaf(p0, lo_f(u0.w), A6); A7 = fmaf(p0, hi_f(u0.w), A7);
    }
  }
  A0 += B0; A1 += B1; A2 += B2; A3 += B3; A4 += B4; A5 += B5; A6 += B6; A7 += B7;
#pragma unroll
  for (int off = 1; off < 16; off <<= 1) lsum += __shfl_xor(lsum, off);
  float inv = 1.f / (lsum + 1.f);
  int4 bv = *(const int4*)(bias + l * 8);
  float o0 = fmaxf(fmaf(A0, inv, lo_f((unsigned)bv.x)), 0.f);
  float o1 = fmaxf(fmaf(A1, inv, hi_f((unsigned)bv.x)), 0.f);
  float o2 = fmaxf(fmaf(A2, inv, lo_f((unsigned)bv.y)), 0.f);
  float o3 = fmaxf(fmaf(A3, inv, hi_f((unsigned)bv.y)), 0.f);
  float o4 = fmaxf(fmaf(A4, inv, lo_f((unsigned)bv.z)), 0.f);
  float o5 = fmaxf(fmaf(A5, inv, hi_f((unsigned)bv.z)), 0.f);
  float o6 = fmaxf(fmaf(A6, inv, lo_f((unsigned)bv.w)), 0.f);
  float o7 = fmaxf(fmaf(A7, inv, hi_f((unsigned)bv.w)), 0.f);
  int4 ov;
  ov.x = (int)pack2(o0, o1); ov.y = (int)pack2(o2, o3);
  ov.z = (int)pack2(o4, o5); ov.w = (int)pack2(o6, o7);
  *(int4*)(out + (size_t)d * 128 + l * 8) = ov;
}

// ---------- FUSED dual-head, 16 lanes/node: lanes 0-7 mu, 8-15 logstd ----------
__global__ __launch_bounds__(256) void k_aggh(
    const int* __restrict__ row_off, const int2* __restrict__ edges,
    const float2* __restrict__ asAB, const float* __restrict__ adA,
    const float* __restrict__ adB,
    const float* __restrict__ la, const float* __restrict__ cptr,
    const u16* __restrict__ xl, const u16* __restrict__ bias,
    float* __restrict__ outf, int n) {
  __shared__ float lpA[16][16];
  __shared__ float lpB[16][16];
  __shared__ int lsv[16][16];
  int tid = blockIdx.x * 256 + threadIdx.x;
  int d = tid >> 4;
  if (d >= n) return;
  int l = threadIdx.x & 15;
  int grp = threadIdx.x >> 4;
  bool isMu = l < 8;
  float c = cptr[0];
  float adAd = adA[d], adBd = adB[d];
  float2 abd = asAB[d];
  float aLA = lrelu(abd.x + adAd + c * la[d]);
  float aLB = lrelu(abd.y + adBd);
  float lsA = 0.f, lsB = 0.f;
  int4 su = *(const int4*)(xl + (size_t)d * 128 + l * 8);
  float A0 = lo_f(su.x), A1 = hi_f(su.x), A2 = lo_f(su.y), A3 = hi_f(su.y);
  float A4 = lo_f(su.z), A5 = hi_f(su.z), A6 = lo_f(su.w), A7 = hi_f(su.w);
  float B0 = 0.f, B1 = 0.f, B2 = 0.f, B3 = 0.f, B4 = 0.f, B5 = 0.f, B6 = 0.f, B7 = 0.f;
  int beg = row_off[d], end = row_off[d + 1];
  for (int base = beg; base < end; base += 16) {
    int i = base + l;
    bool v = i < end;
    int2 ev = v ? edges[i] : make_int2(0, 0);
    float eA = 0.f, eB = 0.f;
    if (v) {
      float2 ab = asAB[ev.x];
      eA = __expf(lrelu(ab.x + adAd + c * bf2f((u16)(ev.y & 0xffff))) - aLA);
      eB = __expf(lrelu(ab.y + adBd) - aLB);
    }
    lsA += eA; lsB += eB;
    lpA[grp][l] = eA; lpB[grp][l] = eB; lsv[grp][l] = ev.x;
    const float* lpp = isMu ? lpA[grp] : lpB[grp];
    int cnt = end - base; if (cnt > 16) cnt = 16;
    int j = 0;
    for (; j + 2 <= cnt; j += 2) {
      float p0 = lpp[j];     int s0 = lsv[grp][j];
      float p1 = lpp[j + 1]; int s1 = lsv[grp][j + 1];
      int4 u0 = *(const int4*)(xl + (size_t)s0 * 128 + l * 8);
      int4 u1 = *(const int4*)(xl + (size_t)s1 * 128 + l * 8);
      A0 = fmaf(p0, lo_f(u0.x), A0); A1 = fmaf(p0, hi_f(u0.x), A1);
      A2 = fmaf(p0, lo_f(u0.y), A2); A3 = fmaf(p0, hi_f(u0.y), A3);
      A4 = fmaf(p0, lo_f(u0.z), A4); A5 = fmaf(p0, hi_f(u0.z), A5);
      A6 = fmaf(p0, lo_f(u0.w), A6); A7 = fmaf(p0, hi_f(u0.w), A7);
      B0 = fmaf(p1, lo_f(u1.x), B0); B1 = fmaf(p1, hi_f(u1.x), B1);
      B2 = fmaf(p1, lo_f(u1.y), B2); B3 = fmaf(p1, hi_f(u1.y), B3);
      B4 = fmaf(p1, lo_f(u1.z), B4); B5 = fmaf(p1, hi_f(u1.z), B5);
      B6 = fmaf(p1, lo_f(u1.w), B6); B7 = fmaf(p1, hi_f(u1.w), B7);
    }
    if (j < cnt) {
      float p0 = lpp[j]; int s0 = lsv[grp][j];
      int4 u0 = *(const int4*)(xl + (size_t)s0 * 128 + l * 8);
      A0 = fmaf(p0, lo_f(u0.x), A0); A1 = fmaf(p0, hi_f(u0.x), A1);
      A2 = fmaf(p0, lo_f(u0.y), A2); A3 = fmaf(p0, hi_f(u0.y), A3);
      A4 = fmaf(p0, lo_f(u0.z), A4); A5 = fmaf(p0, hi_f(u0.z), A5);
      A6 = fmaf(p0, lo_f(u0.w), A6); A7 = fmaf(p0, hi_f(u0.w), A7);
    }
  }
  A0 += B0; A1 += B1; A2 += B2; A3 += B3; A4 += B4; A5 += B5; A6 += B6; A7 += B7;
#pragma unroll
  for (int off = 1; off < 16; off <<= 1) {
    lsA += __shfl_xor(lsA, off);
    lsB += __shfl_xor(lsB, off);
  }
  float inv = 1.f / ((isMu ? lsA : lsB) + 1.f);
  int4 bv = *(const int4*)(bias + l * 8);
  float4 oa, ob;
  oa.x = fmaf(A0, inv, lo_f((unsigned)bv.x));
  oa.y = fmaf(A1, inv, hi_f((unsigned)bv.x));
  oa.z = fmaf(A2, inv, lo_f((unsigned)bv.y));
  oa.w = fmaf(A3, inv, hi_f((unsigned)bv.y));
  ob.x = fmaf(A4, inv, lo_f((unsigned)bv.z));
  ob.y = fmaf(A5, inv, hi_f((unsigned)bv.z));
  ob.z = fmaf(A6, inv, lo_f((unsigned)bv.w));
  ob.w = fmaf(A7, inv, hi_f((unsigned)bv.w));
  float* obase = isMu ? (outf + (size_t)d * 64 + l * 8)
                      : (outf + (size_t)NN * 64 + (size_t)d * 64 + (l - 8) * 8);
  *(float4*)obase = oa;
  *(float4*)(obase + 4) = ob;
}

extern "C" void kernel_launch(void* const* d_in, const int* in_sizes, int n_in,
                              void* d_out, int out_size, void* d_ws, size_t ws_size,
                              hipStream_t stream) {
  (void)in_sizes; (void)n_in;
  const int* ei = (const int*)d_in[1];
  const u16* xb = (const u16*)d_in[0];
  float* outf = (float*)d_out;  // fp32 output

  // d_out scratch: histM (1.23MB) at offset 0 — dead before agg L1 writes h1.
  u16* regionA = (u16*)d_out;                     // h1
  u16* regionB = (u16*)d_out + (size_t)NN * 128;  // h0
  int* histM = (int*)d_out;                       // [NBKP][NBLKP] = 1.23 MB

  char* p = (char*)d_ws;
  auto alloc = [&](size_t bytes) -> char* {
    char* r = p; p += (bytes + 255) & ~(size_t)255; return r;
  };
  int*   row_off   = (int*)alloc((NN + 1) * 4);
  int*   binTot    = (int*)alloc(NBKP * 4);
  int*   bucketBase= (int*)alloc((NBKP + 2) * 4);
  float* la        = (float*)alloc(NN * 4);
  float* asrcA     = (float*)alloc(NN * 4);
  float* adstA     = (float*)alloc(NN * 4);
  float* adstB     = (float*)alloc(NN * 4);
  float2* asAB     = (float2*)alloc((size_t)NN * 8);
  int2*  edges     = (int2*)alloc((size_t)EE * 8);   // final CSR {src, low7|w}
  u16*   WT0       = (u16*)alloc(128 * 128 * 2);
  u16*   WT1       = (u16*)alloc(128 * 128 * 2);
  u16*   WTh       = (u16*)alloc(128 * 128 * 2);
  float* cvals     = (float*)alloc(16);
  u16*   vecc      = (u16*)alloc(9 * 256);
  u16*   xl        = (u16*)alloc((size_t)NN * 128 * 2);  // 25.6 MB

  // stage aliases xl: consumed by k_bucket BEFORE k_gemm0 writes xl.
  int2* stage = (int2*)xl;  // 12.8 MB <= 25.6 MB

  size_t NEED = (size_t)(p - (char*)d_ws);  // ~41.3 MB
  if (ws_size < NEED) {
    k_fillf<<<(out_size + 255) / 256, 256, 0, stream>>>(outf, out_size, 0.125f);
    return;
  }

  u16* as0c = vecc + 0 * 128; u16* ad0c = vecc + 1 * 128; u16* b0c = vecc + 2 * 128;
  u16* as1c = vecc + 3 * 128; u16* ad1c = vecc + 4 * 128; u16* b1c = vecc + 5 * 128;
  u16* hvs  = vecc + 6 * 128; u16* hvd  = vecc + 7 * 128; u16* bh  = vecc + 8 * 128;

  // ---- fused setup ----
  SetupArgs sa;
  sa.cvt[0]  = {d_in[4],  as0c, 128};
  sa.cvt[1]  = {d_in[5],  ad0c, 128};
  sa.cvt[2]  = {d_in[8],  b0c,  128};
  sa.cvt[3]  = {d_in[10], as1c, 128};
  sa.cvt[4]  = {d_in[11], ad1c, 128};
  sa.cvt[5]  = {d_in[14], b1c,  128};
  sa.cvt[6]  = {d_in[16], hvs,      64};  // asm
  sa.cvt[7]  = {d_in[22], hvs + 64, 64};  // asl
  sa.cvt[8]  = {d_in[17], hvd,      64};  // adm
  sa.cvt[9]  = {d_in[23], hvd + 64, 64};  // adl
  sa.cvt[10] = {d_in[20], bh,       64};  // bm
  sa.cvt[11] = {d_in[24], bh + 64,  64};  // bl
  sa.W[0] = d_in[3];  sa.WT[0] = WT0;            sa.WM[0] = 128;
  sa.W[1] = d_in[9];  sa.WT[1] = WT1;            sa.WM[1] = 128;
  sa.W[2] = d_in[15]; sa.WT[2] = WTh;            sa.WM[2] = 64;  // Wm -> rows 0-63
  sa.W[3] = d_in[21]; sa.WT[3] = WTh + 64 * 128; sa.WM[3] = 64;  // Wl -> rows 64-127
  sa.dw[0] = d_in[7];  sa.da[0] = d_in[6];  sa.dm[0] = 128;
  sa.dw[1] = d_in[13]; sa.da[1] = d_in[12]; sa.dm[1] = 128;
  sa.dw[2] = d_in[19]; sa.da[2] = d_in[18]; sa.dm[2] = 64;
  sa.cvals = cvals; sa.xb = xb;
  k_setup<<<12 + 192 + 3, 256, 0, stream>>>(sa);

  const int gblocks = (((NN + 15) / 16) + 3) / 4;
  const int eblocks16 = (int)(((size_t)NN * 16 + 255) / 256);

  // ---- CSR build (zero global atomics) ----
  k_ehist<<<NBLK, 256, 0, stream>>>(ei, histM);
  k_scanA<<<NBK, 512, 0, stream>>>(histM, binTot);
  k_scanB<<<1, 256, 0, stream>>>(binTot, bucketBase, row_off);
  k_escatter<<<NBLK, 256, 0, stream>>>(ei, d_in[2], xb, histM, bucketBase, stage);
  k_bucket<<<NBK, 256, 0, stream>>>(stage, bucketBase, edges, row_off, la);

  // ---- layer 0: x -> xl (overwrites stage, now dead) -> h0(regionB) ----
  k_gemm0<<<gblocks, 256, 0, stream>>>(xb, d_in[0], WT0, as0c, ad0c,
                                       xl, asrcA, adstA, NN);
  k_agg<<<eblocks16, 256, 0, stream>>>(row_off, edges, asrcA, adstA, la,
                                       cvals + 0, xl, b0c, regionB, NN);
  // ---- layer 1 ----
  k_gemm<false><<<gblocks, 256, 0, stream>>>(regionB, WT1, as1c, ad1c,
                                             xl, asrcA, adstA, nullptr, nullptr, NN);
  k_agg<<<eblocks16, 256, 0, stream>>>(row_off, edges, asrcA, adstA, la,
                                       cvals + 1, xl, b1c, regionA, NN);
  // ---- heads ----
  k_gemm<true><<<gblocks, 256, 0, stream>>>(regionA, WTh, hvs, hvd,
                                            xl, nullptr, adstA, asAB, adstB, NN);
  k_aggh<<<eblocks16, 256, 0, stream>>>(row_off, edges, asAB, adstA, adstB,
                                        la, cvals + 2, xl, bh, outf, NN);
}

// Round 8
// 518.095 us; speedup vs baseline: 1.7062x; 1.0157x over previous
//
#include <hip/hip_runtime.h>

#define NN 100000
#define EE 1600000
#define NBK 782          // coarse buckets = ceil(NN/128)
#define NBKP 784
#define NBLK 391         // edge blocks = ceil(EE/4096)
#define NBLKP 392
#define SETB 207         // setup blocks: 12 cvt + 192 transpose + 3 dots

typedef __attribute__((ext_vector_type(8))) __bf16 bf16x8;
typedef __attribute__((ext_vector_type(4))) float f32x4;
typedef unsigned short u16;

__device__ __forceinline__ float bf2f(u16 v) {
  union { unsigned u; float f; } x; x.u = ((unsigned)v) << 16; return x.f;
}
__device__ __forceinline__ u16 f2bf(float f) {
  union { unsigned u; float f; } x; x.f = f;
  x.u += 0x7fffu + ((x.u >> 16) & 1u);
  return (u16)(x.u >> 16);
}
__device__ __forceinline__ float lo_f(unsigned u) {
  union { unsigned u; float f; } x; x.u = u << 16; return x.f;
}
__device__ __forceinline__ float hi_f(unsigned u) {
  union { unsigned u; float f; } x; x.u = u & 0xffff0000u; return x.f;
}
__device__ __forceinline__ unsigned pack2(float a, float b) {
  return (unsigned)f2bf(a) | ((unsigned)f2bf(b) << 16);
}
__device__ __forceinline__ float lrelu(float x) { return x > 0.f ? x : 0.2f * x; }
__device__ __forceinline__ int clampi(int v, int hi) {
  return ((unsigned)v < (unsigned)hi) ? v : 0;
}
__device__ __forceinline__ float ldf(const void* p, size_t i, int fl) {
  return fl ? ((const float*)p)[i] : bf2f(((const u16*)p)[i]);
}

// ---- per-wave inline dtype detection ----
__device__ __forceinline__ int wave_fdetect(const u16* __restrict__ xb) {
  int lane = threadIdx.x & 63;
  int bad = 0;
#pragma unroll
  for (int j = 0; j < 4; ++j) {
    float a = fabsf(bf2f(xb[lane * 4 + j]));
    bad |= (!(a == a) || a > 1e6f) ? 1 : 0;
  }
  return (__ballot(bad) != 0ull) ? 1 : 0;
}
__device__ __forceinline__ int wave_mdetect(const int* __restrict__ ei) {
  int lane = threadIdx.x & 63;
  int v = (lane < 32) ? ei[2 * lane + 1] : 0;
  return (__ballot(v != 0) == 0ull) ? 1 : 0;
}

// ---------- sentinel fill ----------
__global__ void k_fillf(float* __restrict__ o, int n, float v) {
  int i = blockIdx.x * 256 + threadIdx.x;
  if (i < n) o[i] = v;
}

// ---------- fused setup (+ coarse edge histogram) ----------
struct CvtDesc { const void* src; u16* dst; int n; };
struct SetupArgs {
  CvtDesc cvt[12];
  const void* W[4]; u16* WT[4]; int WM[4];
  const void* dw[3]; const void* da[3]; int dm[3];
  float* cvals;
  const u16* xb;
  const int* ei;
  int* histM;
};
__global__ __launch_bounds__(256) void k_setup(SetupArgs a) {
  __shared__ int h[NBKP];
  int b = blockIdx.x, t = threadIdx.x;
  if (b >= SETB) {  // ---- ehist part: blocks [SETB, SETB+NBLK) ----
    int blk = b - SETB;
    int m_ = wave_mdetect(a.ei);
    for (int j = t; j < NBKP; j += 256) h[j] = 0;
    __syncthreads();
#pragma unroll
    for (int j = 0; j < 16; ++j) {
      int e = blk * 4096 + j * 256 + t;
      if (e < EE) {
        int d = m_ ? a.ei[2 * (size_t)(EE + e)] : a.ei[EE + e];
        d = clampi(d, NN);
        atomicAdd(&h[d >> 7], 1);
      }
    }
    __syncthreads();
    for (int j = t; j < NBKP; j += 256) a.histM[j * NBLKP + blk] = h[j];
    return;
  }
  if (b < 12) {  // small-vector conversions
    int fl = wave_fdetect(a.xb);
    const void* src = a.cvt[b].src; u16* dst = a.cvt[b].dst; int n = a.cvt[b].n;
    for (int i = t; i < n; i += 256)
      dst[i] = fl ? f2bf(((const float*)src)[i]) : ((const u16*)src)[i];
    return;
  }
  b -= 12;
  if (b < 192) {  // weight transposes: W0:64, W1:64, Wm:32, Wl:32 blocks
    int fl = wave_fdetect(a.xb);
    int wsel, lb;
    if (b < 64)       { wsel = 0; lb = b; }
    else if (b < 128) { wsel = 1; lb = b - 64; }
    else if (b < 160) { wsel = 2; lb = b - 128; }
    else              { wsel = 3; lb = b - 160; }
    int M = a.WM[wsel];
    int i = lb * 256 + t;
    if (i < 128 * M) {
      int k = i / M, m = i % M;
      a.WT[wsel][m * 128 + k] = f2bf(ldf(a.W[wsel], i, fl));
    }
    return;
  }
  b -= 192;
  if (b < 3) {  // c = dot(We[0,:], a_e)
    if (t < 64) {
      int fl = wave_fdetect(a.xb);
      float s = 0.f; int m = a.dm[b];
      for (int j = t; j < m; j += 64) s += ldf(a.dw[b], j, fl) * ldf(a.da[b], j, fl);
      for (int off = 32; off; off >>= 1) s += __shfl_xor(s, off);
      if (t == 0) a.cvals[b] = s;
    }
    return;
  }
}

// ---------- per-bucket exclusive prefix over blocks (in-place) + bucket totals ----------
__global__ __launch_bounds__(512) void k_scanA(int* __restrict__ histM,
                                               int* __restrict__ binTot) {
  int b = blockIdx.x, t = threadIdx.x;
  int v = (t < NBLK) ? histM[b * NBLKP + t] : 0;
  int lane = t & 63, w = t >> 6;
  int sc = v;
  for (int off = 1; off < 64; off <<= 1) {
    int o = __shfl_up(sc, off); if (lane >= off) sc += o;
  }
  __shared__ int wt[8];
  if (lane == 63) wt[w] = sc;
  __syncthreads();
  int add = 0;
  for (int k = 0; k < w; ++k) add += wt[k];
  int excl = sc - v + add;
  if (t < NBLK) histM[b * NBLKP + t] = excl;
  if (t == 511) binTot[b] = excl;  // v=0 here -> excl = total
}

// ---------- exclusive scan of bucket totals -> bucketBase ----------
__global__ __launch_bounds__(256) void k_scanB(const int* __restrict__ binTot,
                                               int* __restrict__ bucketBase,
                                               int* __restrict__ row_off) {
  int t = threadIdx.x;
  int v[4]; int s = 0;
#pragma unroll
  for (int j = 0; j < 4; ++j) {
    int idx = t * 4 + j;
    v[j] = (idx < NBK) ? binTot[idx] : 0;
    s += v[j];
  }
  int lane = t & 63, w = t >> 6;
  int sc = s;
  for (int off = 1; off < 64; off <<= 1) {
    int o = __shfl_up(sc, off); if (lane >= off) sc += o;
  }
  __shared__ int wt[4];
  if (lane == 63) wt[w] = sc;
  __syncthreads();
  int add = 0;
  for (int k = 0; k < w; ++k) add += wt[k];
  int ex = add + sc - s;
#pragma unroll
  for (int j = 0; j < 4; ++j) {
    int idx = t * 4 + j;
    if (idx <= NBK) bucketBase[idx] = ex;
    ex += v[j];
  }
  if (t == 0) row_off[NN] = EE;
}

// ---------- GEMM body: xl = A @ W + logit epilogues ----------
template<bool DUAL>
__device__ __forceinline__ void gemm_body(
    int bid, int fl, const void* __restrict__ Araw,
    const u16* __restrict__ WT,
    const u16* __restrict__ avs, const u16* __restrict__ avd,
    u16* __restrict__ xl,
    float* __restrict__ asrc, float* __restrict__ adst,
    float2* __restrict__ asAB, float* __restrict__ adstB, int n) {
  const int K = 128;
  int lane = threadIdx.x & 63;
  int wave = threadIdx.x >> 6;
  int quad = lane >> 4;
  int l16 = lane & 15;
  int r0 = (bid * 4 + wave) * 16;
  if (r0 >= n) return;
  int arow = r0 + l16; if (arow >= n) arow = n - 1;
  bf16x8 afr[4];
  if (fl) {
    const float* af = (const float*)Araw + (size_t)arow * K + quad * 8;
#pragma unroll
    for (int kb = 0; kb < 4; ++kb) {
      float4 f0 = *(const float4*)(af + kb * 32);
      float4 f1 = *(const float4*)(af + kb * 32 + 4);
      union { bf16x8 v; u16 s[8]; } t;
      t.s[0] = f2bf(f0.x); t.s[1] = f2bf(f0.y); t.s[2] = f2bf(f0.z); t.s[3] = f2bf(f0.w);
      t.s[4] = f2bf(f1.x); t.s[5] = f2bf(f1.y); t.s[6] = f2bf(f1.z); t.s[7] = f2bf(f1.w);
      afr[kb] = t.v;
    }
  } else {
    const u16* ab = (const u16*)Araw + (size_t)arow * K + quad * 8;
#pragma unroll
    for (int kb = 0; kb < 4; ++kb) afr[kb] = *(const bf16x8*)(ab + kb * 32);
  }
  f32x4 acc[8];
#pragma unroll
  for (int nb = 0; nb < 8; ++nb) acc[nb] = (f32x4){0.f, 0.f, 0.f, 0.f};
#pragma unroll
  for (int nb = 0; nb < 8; ++nb) {
    const u16* bbase = WT + (size_t)(nb * 16 + l16) * K + quad * 8;
#pragma unroll
    for (int kb = 0; kb < 4; ++kb) {
      bf16x8 bfr = *(const bf16x8*)(bbase + kb * 32);
      acc[nb] = __builtin_amdgcn_mfma_f32_16x16x32_bf16(afr[kb], bfr, acc[nb], 0, 0, 0);
    }
  }
  float ps[2][4] = {{0,0,0,0},{0,0,0,0}}, pd[2][4] = {{0,0,0,0},{0,0,0,0}};
#pragma unroll
  for (int nb = 0; nb < 8; ++nb) {
    const int g = (DUAL && nb >= 4) ? 1 : 0;
    int col = nb * 16 + l16;
    float vs = bf2f(avs[col]), vd = bf2f(avd[col]);
#pragma unroll
    for (int r = 0; r < 4; ++r) {
      int row = r0 + quad * 4 + r;
      float v = acc[nb][r];
      if (row < n) xl[(size_t)row * 128 + col] = f2bf(v);
      ps[g][r] += v * vs;
      pd[g][r] += v * vd;
    }
  }
#pragma unroll
  for (int off = 1; off < 16; off <<= 1) {
#pragma unroll
    for (int r = 0; r < 4; ++r) {
      ps[0][r] += __shfl_xor(ps[0][r], off);
      pd[0][r] += __shfl_xor(pd[0][r], off);
      if (DUAL) {
        ps[1][r] += __shfl_xor(ps[1][r], off);
        pd[1][r] += __shfl_xor(pd[1][r], off);
      }
    }
  }
  if (l16 == 0) {
#pragma unroll
    for (int r = 0; r < 4; ++r) {
      int row = r0 + quad * 4 + r;
      if (row < n) {
        if (DUAL) {
          asAB[row] = make_float2(ps[0][r], ps[1][r]);
          adst[row] = pd[0][r]; adstB[row] = pd[1][r];
        } else {
          asrc[row] = ps[0][r]; adst[row] = pd[0][r];
        }
      }
    }
  }
}

// ---------- MERGED: bucket scatter (LDS ranks) + layer-0 GEMM (independent) ----------
__global__ __launch_bounds__(256) void k_esgemm(
    const int* __restrict__ ei, const void* __restrict__ ew,
    const u16* __restrict__ xb, const int* __restrict__ histM,
    const int* __restrict__ bucketBase, int2* __restrict__ stage,
    const void* __restrict__ Araw, const u16* __restrict__ WT,
    const u16* __restrict__ avs, const u16* __restrict__ avd,
    u16* __restrict__ xl, float* __restrict__ asrc, float* __restrict__ adst, int n) {
  __shared__ int lbase[NBKP];
  __shared__ int cur[NBKP];
  if ((int)blockIdx.x >= NBLK) {  // ---- gemm0 part ----
    int fl = wave_fdetect(xb);
    gemm_body<false>((int)blockIdx.x - NBLK, fl, Araw, WT, avs, avd,
                     xl, asrc, adst, nullptr, nullptr, n);
    return;
  }
  // ---- escatter part ----
  int blk = blockIdx.x, t = threadIdx.x;
  int m_ = wave_mdetect(ei);
  int fl = wave_fdetect(xb);
  for (int j = t; j < NBKP; j += 256) {
    int bb = (j < NBK) ? (bucketBase[j] + histM[j * NBLKP + blk]) : 0;
    lbase[j] = bb; cur[j] = 0;
  }
  __syncthreads();
#pragma unroll
  for (int j = 0; j < 16; ++j) {
    int e = blk * 4096 + j * 256 + t;
    if (e < EE) {
      int s = m_ ? ei[2 * (size_t)e] : ei[e];
      int d = m_ ? ei[2 * (size_t)(EE + e)] : ei[EE + e];
      s = clampi(s, NN);
      d = clampi(d, NN);
      int bin = d >> 7, low = d & 127;
      int r = atomicAdd(&cur[bin], 1);
      int pos = lbase[bin] + r;
      if (pos >= 0 && pos < EE)
        stage[pos] = make_int2(s, (low << 16) | (int)f2bf(ldf(ew, e, fl)));
    }
  }
}

// ---------- per-bucket counting sort by low7 -> final CSR + row_off + la ----------
__global__ __launch_bounds__(256) void k_bucket(
    const int2* __restrict__ stage, const int* __restrict__ bucketBase,
    int2* __restrict__ edges, int* __restrict__ row_off, float* __restrict__ la) {
  __shared__ int hist[128];
  __shared__ float wsum[128];
  __shared__ int pref[128];
  __shared__ int cur[128];
  int b = blockIdx.x, t = threadIdx.x;
  int base = bucketBase[b], n = bucketBase[b + 1] - base;
  if (t < 128) { hist[t] = 0; wsum[t] = 0.f; cur[t] = 0; }
  __syncthreads();
  for (int i = t; i < n; i += 256) {
    int2 it = stage[base + i];
    int bin = (it.y >> 16) & 127;
    atomicAdd(&hist[bin], 1);
    atomicAdd(&wsum[bin], bf2f((u16)(it.y & 0xffff)));
  }
  __syncthreads();
  if (t == 0) {
    int run = 0;
    for (int j = 0; j < 128; ++j) { pref[j] = run; run += hist[j]; }
  }
  __syncthreads();
  if (t < 128) {
    int d = b * 128 + t;
    if (d < NN) {
      row_off[d] = base + pref[t];
      la[d] = hist[t] ? wsum[t] / (float)hist[t] : 0.f;
    }
  }
  for (int i = t; i < n; i += 256) {
    int2 it = stage[base + i];
    int bin = (it.y >> 16) & 127;
    int r = atomicAdd(&cur[bin], 1);
    edges[base + pref[bin] + r] = it;
  }
}

// ---------- standalone GEMM (bf16 A) ----------
template<bool DUAL>
__global__ __launch_bounds__(256) void k_gemm(
    const u16* __restrict__ A, const u16* __restrict__ WT,
    const u16* __restrict__ avs, const u16* __restrict__ avd,
    u16* __restrict__ xl, float* __restrict__ asrc, float* __restrict__ adst,
    float2* __restrict__ asAB, float* __restrict__ adstB, int n) {
  gemm_body<DUAL>(blockIdx.x, 0, A, WT, avs, avd, xl, asrc, adst, asAB, adstB, n);
}

// ---------- FUSED softmax+aggregation, 16 lanes/node, unroll-4 int4 gathers ----------
__global__ __launch_bounds__(256) void k_agg(
    const int* __restrict__ row_off, const int2* __restrict__ edges,
    const float* __restrict__ asrc, const float* __restrict__ adst,
    const float* __restrict__ la, const float* __restrict__ cptr,
    const u16* __restrict__ xl, const u16* __restrict__ bias,
    u16* __restrict__ out, int n) {
  __shared__ float lp[16][16];
  __shared__ int lsv[16][16];
  int tid = blockIdx.x * 256 + threadIdx.x;
  int d = tid >> 4;
  if (d >= n) return;
  int l = threadIdx.x & 15;
  int grp = threadIdx.x >> 4;
  float c = cptr[0];
  float ad = adst[d];
  float aL = lrelu(asrc[d] + ad + c * la[d]);
  float lsum = 0.f;
  int4 su = *(const int4*)(xl + (size_t)d * 128 + l * 8);
  float A0 = lo_f(su.x), A1 = hi_f(su.x), A2 = lo_f(su.y), A3 = hi_f(su.y);
  float A4 = lo_f(su.z), A5 = hi_f(su.z), A6 = lo_f(su.w), A7 = hi_f(su.w);
  float B0 = 0.f, B1 = 0.f, B2 = 0.f, B3 = 0.f, B4 = 0.f, B5 = 0.f, B6 = 0.f, B7 = 0.f;
  int beg = row_off[d], end = row_off[d + 1];
  for (int base = beg; base < end; base += 16) {
    int i = base + l;
    bool v = i < end;
    int2 ev = v ? edges[i] : make_int2(0, 0);
    float e = 0.f;
    if (v) e = __expf(lrelu(asrc[ev.x] + ad + c * bf2f((u16)(ev.y & 0xffff))) - aL);
    lsum += e;
    lp[grp][l] = e; lsv[grp][l] = ev.x;
    int cnt = end - base; if (cnt > 16) cnt = 16;
    int j = 0;
    for (; j + 4 <= cnt; j += 4) {   // 4 loads in flight per thread
      float p0 = lp[grp][j + 0]; int s0 = lsv[grp][j + 0];
      float p1 = lp[grp][j + 1]; int s1 = lsv[grp][j + 1];
      float p2 = lp[grp][j + 2]; int s2 = lsv[grp][j + 2];
      float p3 = lp[grp][j + 3]; int s3 = lsv[grp][j + 3];
      int4 u0 = *(const int4*)(xl + (size_t)s0 * 128 + l * 8);
      int4 u1 = *(const int4*)(xl + (size_t)s1 * 128 + l * 8);
      int4 u2 = *(const int4*)(xl + (size_t)s2 * 128 + l * 8);
      int4 u3 = *(const int4*)(xl + (size_t)s3 * 128 + l * 8);
      A0 = fmaf(p0, lo_f(u0.x), A0); A1 = fmaf(p0, hi_f(u0.x), A1);
      A2 = fmaf(p0, lo_f(u0.y), A2); A3 = fmaf(p0, hi_f(u0.y), A3);
      A4 = fmaf(p0, lo_f(u0.z), A4); A5 = fmaf(p0, hi_f(u0.z), A5);
      A6 = fmaf(p0, lo_f(u0.w), A6); A7 = fmaf(p0, hi_f(u0.w), A7);
      B0 = fmaf(p1, lo_f(u1.x), B0); B1 = fmaf(p1, hi_f(u1.x), B1);
      B2 = fmaf(p1, lo_f(u1.y), B2); B3 = fmaf(p1, hi_f(u1.y), B3);
      B4 = fmaf(p1, lo_f(u1.z), B4); B5 = fmaf(p1, hi_f(u1.z), B5);
      B6 = fmaf(p1, lo_f(u1.w), B6); B7 = fmaf(p1, hi_f(u1.w), B7);
      A0 = fmaf(p2, lo_f(u2.x), A0); A1 = fmaf(p2, hi_f(u2.x), A1);
      A2 = fmaf(p2, lo_f(u2.y), A2); A3 = fmaf(p2, hi_f(u2.y), A3);
      A4 = fmaf(p2, lo_f(u2.z), A4); A5 = fmaf(p2, hi_f(u2.z), A5);
      A6 = fmaf(p2, lo_f(u2.w), A6); A7 = fmaf(p2, hi_f(u2.w), A7);
      B0 = fmaf(p3, lo_f(u3.x), B0); B1 = fmaf(p3, hi_f(u3.x), B1);
      B2 = fmaf(p3, lo_f(u3.y), B2); B3 = fmaf(p3, hi_f(u3.y), B3);
      B4 = fmaf(p3, lo_f(u3.z), B4); B5 = fmaf(p3, hi_f(u3.z), B5);
      B6 = fmaf(p3, lo_f(u3.w), B6); B7 = fmaf(p3, hi_f(u3.w), B7);
    }
    for (; j + 2 <= cnt; j += 2) {
      float p0 = lp[grp][j];     int s0 = lsv[grp][j];
      float p1 = lp[grp][j + 1]; int s1 = lsv[grp][j + 1];
      int4 u0 = *(const int4*)(xl + (size_t)s0 * 128 + l * 8);
      int4 u1 = *(const int4*)(xl + (size_t)s1 * 128 + l * 8);
      A0 = fmaf(p0, lo_f(u0.x), A0); A1 = fmaf(p0, hi_f(u0.x), A1);
      A2 = fmaf(p0, lo_f(u0.y), A2); A3 = fmaf(p0, hi_f(u0.y), A3);
      A4 = fmaf(p0, lo_f(u0.z), A4); A5 = fmaf(p0, hi_f(u0.z), A5);
      A6 = fmaf(p0, lo_f(u0.w), A6); A7 = fmaf(p0, hi_f(u0.w), A7);
      B0 = fmaf(p1, lo_f(u1.x), B0); B1 = fmaf(p1, hi_f(u1.x), B1);
      B2 = fmaf(p1, lo_f(u1.y), B2); B3 = fmaf(p1, hi_f(u1.y), B3);
      B4 = fmaf(p1, lo_f(u1.z), B4); B5 = fmaf(p1, hi_f(u1.z), B5);
      B6 = fmaf(p1, lo_f(u1.w), B6); B7 = fmaf(p1, hi_f(u1.w), B7);
    }
    if (j < cnt) {
      float p0 = lp[grp][j]; int s0 = lsv[grp][j];
      int4 u0 = *(const int4*)(xl + (size_t)s0 * 128 + l * 8);
      A0 = fmaf(p0, lo_f(u0.x), A0); A1 = fmaf(p0, hi_f(u0.x), A1);
      A2 = fmaf(p0, lo_f(u0.y), A2); A3 = fmaf(p0, hi_f(u0.y), A3);
      A4 = fmaf(p0, lo_f(u0.z), A4); A5 = fmaf(p0, hi_f(u0.z), A5);
      A6 = fmaf(p0, lo_f(u0.w), A6); A7 = fmaf(p0, hi_f(u0.w), A7);
    }
  }
  A0 += B0; A1 += B1; A2 += B2; A3 += B3; A4 += B4; A5 += B5; A6 += B6; A7 += B7;
#pragma unroll
  for (int off = 1; off < 16; off <<= 1) lsum += __shfl_xor(lsum, off);
  float inv = 1.f / (lsum + 1.f);
  int4 bv = *(const int4*)(bias + l * 8);
  float o0 = fmaxf(fmaf(A0, inv, lo_f((unsigned)bv.x)), 0.f);
  float o1 = fmaxf(fmaf(A1, inv, hi_f((unsigned)bv.x)), 0.f);
  float o2 = fmaxf(fmaf(A2, inv, lo_f((unsigned)bv.y)), 0.f);
  float o3 = fmaxf(fmaf(A3, inv, hi_f((unsigned)bv.y)), 0.f);
  float o4 = fmaxf(fmaf(A4, inv, lo_f((unsigned)bv.z)), 0.f);
  float o5 = fmaxf(fmaf(A5, inv, hi_f((unsigned)bv.z)), 0.f);
  float o6 = fmaxf(fmaf(A6, inv, lo_f((unsigned)bv.w)), 0.f);
  float o7 = fmaxf(fmaf(A7, inv, hi_f((unsigned)bv.w)), 0.f);
  int4 ov;
  ov.x = (int)pack2(o0, o1); ov.y = (int)pack2(o2, o3);
  ov.z = (int)pack2(o4, o5); ov.w = (int)pack2(o6, o7);
  *(int4*)(out + (size_t)d * 128 + l * 8) = ov;
}

// ---------- FUSED dual-head, 16 lanes/node, unroll-4: lanes 0-7 mu, 8-15 logstd ----------
__global__ __launch_bounds__(256) void k_aggh(
    const int* __restrict__ row_off, const int2* __restrict__ edges,
    const float2* __restrict__ asAB, const float* __restrict__ adA,
    const float* __restrict__ adB,
    const float* __restrict__ la, const float* __restrict__ cptr,
    const u16* __restrict__ xl, const u16* __restrict__ bias,
    float* __restrict__ outf, int n) {
  __shared__ float lpA[16][16];
  __shared__ float lpB[16][16];
  __shared__ int lsv[16][16];
  int tid = blockIdx.x * 256 + threadIdx.x;
  int d = tid >> 4;
  if (d >= n) return;
  int l = threadIdx.x & 15;
  int grp = threadIdx.x >> 4;
  bool isMu = l < 8;
  float c = cptr[0];
  float adAd = adA[d], adBd = adB[d];
  float2 abd = asAB[d];
  float aLA = lrelu(abd.x + adAd + c * la[d]);
  float aLB = lrelu(abd.y + adBd);
  float lsA = 0.f, lsB = 0.f;
  int4 su = *(const int4*)(xl + (size_t)d * 128 + l * 8);
  float A0 = lo_f(su.x), A1 = hi_f(su.x), A2 = lo_f(su.y), A3 = hi_f(su.y);
  float A4 = lo_f(su.z), A5 = hi_f(su.z), A6 = lo_f(su.w), A7 = hi_f(su.w);
  float B0 = 0.f, B1 = 0.f, B2 = 0.f, B3 = 0.f, B4 = 0.f, B5 = 0.f, B6 = 0.f, B7 = 0.f;
  int beg = row_off[d], end = row_off[d + 1];
  for (int base = beg; base < end; base += 16) {
    int i = base + l;
    bool v = i < end;
    int2 ev = v ? edges[i] : make_int2(0, 0);
    float eA = 0.f, eB = 0.f;
    if (v) {
      float2 ab = asAB[ev.x];
      eA = __expf(lrelu(ab.x + adAd + c * bf2f((u16)(ev.y & 0xffff))) - aLA);
      eB = __expf(lrelu(ab.y + adBd) - aLB);
    }
    lsA += eA; lsB += eB;
    lpA[grp][l] = eA; lpB[grp][l] = eB; lsv[grp][l] = ev.x;
    const float* lpp = isMu ? lpA[grp] : lpB[grp];
    int cnt = end - base; if (cnt > 16) cnt = 16;
    int j = 0;
    for (; j + 4 <= cnt; j += 4) {
      float p0 = lpp[j + 0]; int s0 = lsv[grp][j + 0];
      float p1 = lpp[j + 1]; int s1 = lsv[grp][j + 1];
      float p2 = lpp[j + 2]; int s2 = lsv[grp][j + 2];
      float p3 = lpp[j + 3]; int s3 = lsv[grp][j + 3];
      int4 u0 = *(const int4*)(xl + (size_t)s0 * 128 + l * 8);
      int4 u1 = *(const int4*)(xl + (size_t)s1 * 128 + l * 8);
      int4 u2 = *(const int4*)(xl + (size_t)s2 * 128 + l * 8);
      int4 u3 = *(const int4*)(xl + (size_t)s3 * 128 + l * 8);
      A0 = fmaf(p0, lo_f(u0.x), A0); A1 = fmaf(p0, hi_f(u0.x), A1);
      A2 = fmaf(p0, lo_f(u0.y), A2); A3 = fmaf(p0, hi_f(u0.y), A3);
      A4 = fmaf(p0, lo_f(u0.z), A4); A5 = fmaf(p0, hi_f(u0.z), A5);
      A6 = fmaf(p0, lo_f(u0.w), A6); A7 = fmaf(p0, hi_f(u0.w), A7);
      B0 = fmaf(p1, lo_f(u1.x), B0); B1 = fmaf(p1, hi_f(u1.x), B1);
      B2 = fmaf(p1, lo_f(u1.y), B2); B3 = fmaf(p1, hi_f(u1.y), B3);
      B4 = fmaf(p1, lo_f(u1.z), B4); B5 = fmaf(p1, hi_f(u1.z), B5);
      B6 = fmaf(p1, lo_f(u1.w), B6); B7 = fmaf(p1, hi_f(u1.w), B7);
      A0 = fmaf(p2, lo_f(u2.x), A0); A1 = fmaf(p2, hi_f(u2.x), A1);
      A2 = fmaf(p2, lo_f(u2.y), A2); A3 = fmaf(p2, hi_f(u2.y), A3);
      A4 = fmaf(p2, lo_f(u2.z), A4); A5 = fmaf(p2, hi_f(u2.z), A5);
      A6 = fmaf(p2, lo_f(u2.w), A6); A7 = fmaf(p2, hi_f(u2.w), A7);
      B0 = fmaf(p3, lo_f(u3.x), B0); B1 = fmaf(p3, hi_f(u3.x), B1);
      B2 = fmaf(p3, lo_f(u3.y), B2); B3 = fmaf(p3, hi_f(u3.y), B3);
      B4 = fmaf(p3, lo_f(u3.z), B4); B5 = fmaf(p3, hi_f(u3.z), B5);
      B6 = fmaf(p3, lo_f(u3.w), B6); B7 = fmaf(p3, hi_f(u3.w), B7);
    }
    for (; j + 2 <= cnt; j += 2) {
      float p0 = lpp[j];     int s0 = lsv[grp][j];
      float p1 = lpp[j + 1]; int s1 = lsv[grp][j + 1];
      int4 u0 = *(const int4*)(xl + (size_t)s0 * 128 + l * 8);
      int4 u1 = *(const int4*)(xl + (size_t)s1 * 128 + l * 8);
      A0 = fmaf(p0, lo_f(u0.x), A0); A1 = fmaf(p0, hi_f(u0.x), A1);
      A2 = fmaf(p0, lo_f(u0.y), A2); A3 = fmaf(p0, hi_f(u0.y), A3);
      A4 = fmaf(p0, lo_f(u0.z), A4); A5 = fmaf(p0, hi_f(u0.z), A5);
      A6 = fmaf(p0, lo_f(u0.w), A6); A7 = fmaf(p0, hi_f(u0.w), A7);
      B0 = fmaf(p1, lo_f(u1.x), B0); B1 = fmaf(p1, hi_f(u1.x), B1);
      B2 = fmaf(p1, lo_f(u1.y), B2); B3 = fmaf(p1, hi_f(u1.y), B3);
      B4 = fmaf(p1, lo_f(u1.z), B4); B5 = fmaf(p1, hi_f(u1.z), B5);
      B6 = fmaf(p1, lo_f(u1.w), B6); B7 = fmaf(p1, hi_f(u1.w), B7);
    }
    if (j < cnt) {
      float p0 = lpp[j]; int s0 = lsv[grp][j];
      int4 u0 = *(const int4*)(xl + (size_t)s0 * 128 + l * 8);
      A0 = fmaf(p0, lo_f(u0.x), A0); A1 = fmaf(p0, hi_f(u0.x), A1);
      A2 = fmaf(p0, lo_f(u0.y), A2); A3 = fmaf(p0, hi_f(u0.y), A3);
      A4 = fmaf(p0, lo_f(u0.z), A4); A5 = fmaf(p0, hi_f(u0.z), A5);
      A6 = fmaf(p0, lo_f(u0.w), A6); A7 = fmaf(p0, hi_f(u0.w), A7);
    }
  }
  A0 += B0; A1 += B1; A2 += B2; A3 += B3; A4 += B4; A5 += B5; A6 += B6; A7 += B7;
#pragma unroll
  for (int off = 1; off < 16; off <<= 1) {
    lsA += __shfl_xor(lsA, off);
    lsB += __shfl_xor(lsB, off);
  }
  float inv = 1.f / ((isMu ? lsA : lsB) + 1.f);
  int4 bv = *(const int4*)(bias + l * 8);
  float4 oa, ob;
  oa.x = fmaf(A0, inv, lo_f((unsigned)bv.x));
  oa.y = fmaf(A1, inv, hi_f((unsigned)bv.x));
  oa.z = fmaf(A2, inv, lo_f((unsigned)bv.y));
  oa.w = fmaf(A3, inv, hi_f((unsigned)bv.y));
  ob.x = fmaf(A4, inv, lo_f((unsigned)bv.z));
  ob.y = fmaf(A5, inv, hi_f((unsigned)bv.z));
  ob.z = fmaf(A6, inv, lo_f((unsigned)bv.w));
  ob.w = fmaf(A7, inv, hi_f((unsigned)bv.w));
  float* obase = isMu ? (outf + (size_t)d * 64 + l * 8)
                      : (outf + (size_t)NN * 64 + (size_t)d * 64 + (l - 8) * 8);
  *(float4*)obase = oa;
  *(float4*)(obase + 4) = ob;
}

extern "C" void kernel_launch(void* const* d_in, const int* in_sizes, int n_in,
                              void* d_out, int out_size, void* d_ws, size_t ws_size,
                              hipStream_t stream) {
  (void)in_sizes; (void)n_in;
  const int* ei = (const int*)d_in[1];
  const u16* xb = (const u16*)d_in[0];
  float* outf = (float*)d_out;  // fp32 output

  // d_out scratch (dead before its region is written as output):
  //   histM: [0 .. 1.23MB)            consumed by k_esgemm/scanA
  //   stage: [2MB .. 14.8MB)          consumed by k_bucket (before agg L1 -> h1)
  u16* regionA = (u16*)d_out;                     // h1 (agg L1 output)
  u16* regionB = (u16*)d_out + (size_t)NN * 128;  // h0 (agg L0 output)
  int* histM = (int*)d_out;
  int2* stage = (int2*)((char*)d_out + (size_t)2 * 1024 * 1024);

  char* p = (char*)d_ws;
  auto alloc = [&](size_t bytes) -> char* {
    char* r = p; p += (bytes + 255) & ~(size_t)255; return r;
  };
  int*   row_off   = (int*)alloc((NN + 1) * 4);
  int*   binTot    = (int*)alloc(NBKP * 4);
  int*   bucketBase= (int*)alloc((NBKP + 2) * 4);
  float* la        = (float*)alloc(NN * 4);
  float* asrcA     = (float*)alloc(NN * 4);
  float* adstA     = (float*)alloc(NN * 4);
  float* adstB     = (float*)alloc(NN * 4);
  float2* asAB     = (float2*)alloc((size_t)NN * 8);
  int2*  edges     = (int2*)alloc((size_t)EE * 8);   // final CSR {src, low7|w}
  u16*   WT0       = (u16*)alloc(128 * 128 * 2);
  u16*   WT1       = (u16*)alloc(128 * 128 * 2);
  u16*   WTh       = (u16*)alloc(128 * 128 * 2);
  float* cvals     = (float*)alloc(16);
  u16*   vecc      = (u16*)alloc(9 * 256);
  u16*   xl        = (u16*)alloc((size_t)NN * 128 * 2);  // 25.6 MB

  size_t NEED = (size_t)(p - (char*)d_ws);  // ~41.3 MB
  if (ws_size < NEED) {
    k_fillf<<<(out_size + 255) / 256, 256, 0, stream>>>(outf, out_size, 0.125f);
    return;
  }

  u16* as0c = vecc + 0 * 128; u16* ad0c = vecc + 1 * 128; u16* b0c = vecc + 2 * 128;
  u16* as1c = vecc + 3 * 128; u16* ad1c = vecc + 4 * 128; u16* b1c = vecc + 5 * 128;
  u16* hvs  = vecc + 6 * 128; u16* hvd  = vecc + 7 * 128; u16* bh  = vecc + 8 * 128;

  // ---- fused setup + ehist ----
  SetupArgs sa;
  sa.cvt[0]  = {d_in[4],  as0c, 128};
  sa.cvt[1]  = {d_in[5],  ad0c, 128};
  sa.cvt[2]  = {d_in[8],  b0c,  128};
  sa.cvt[3]  = {d_in[10], as1c, 128};
  sa.cvt[4]  = {d_in[11], ad1c, 128};
  sa.cvt[5]  = {d_in[14], b1c,  128};
  sa.cvt[6]  = {d_in[16], hvs,      64};  // asm
  sa.cvt[7]  = {d_in[22], hvs + 64, 64};  // asl
  sa.cvt[8]  = {d_in[17], hvd,      64};  // adm
  sa.cvt[9]  = {d_in[23], hvd + 64, 64};  // adl
  sa.cvt[10] = {d_in[20], bh,       64};  // bm
  sa.cvt[11] = {d_in[24], bh + 64,  64};  // bl
  sa.W[0] = d_in[3];  sa.WT[0] = WT0;            sa.WM[0] = 128;
  sa.W[1] = d_in[9];  sa.WT[1] = WT1;            sa.WM[1] = 128;
  sa.W[2] = d_in[15]; sa.WT[2] = WTh;            sa.WM[2] = 64;  // Wm -> rows 0-63
  sa.W[3] = d_in[21]; sa.WT[3] = WTh + 64 * 128; sa.WM[3] = 64;  // Wl -> rows 64-127
  sa.dw[0] = d_in[7];  sa.da[0] = d_in[6];  sa.dm[0] = 128;
  sa.dw[1] = d_in[13]; sa.da[1] = d_in[12]; sa.dm[1] = 128;
  sa.dw[2] = d_in[19]; sa.da[2] = d_in[18]; sa.dm[2] = 64;
  sa.cvals = cvals; sa.xb = xb; sa.ei = ei; sa.histM = histM;
  k_setup<<<SETB + NBLK, 256, 0, stream>>>(sa);

  const int gblocks = (((NN + 15) / 16) + 3) / 4;
  const int eblocks16 = (int)(((size_t)NN * 16 + 255) / 256);

  // ---- CSR offsets ----
  k_scanA<<<NBK, 512, 0, stream>>>(histM, binTot);
  k_scanB<<<1, 256, 0, stream>>>(binTot, bucketBase, row_off);
  // ---- bucket scatter co-resident with layer-0 GEMM (independent) ----
  k_esgemm<<<NBLK + gblocks, 256, 0, stream>>>(ei, d_in[2], xb, histM, bucketBase,
                                               stage, d_in[0], WT0, as0c, ad0c,
                                               xl, asrcA, adstA, NN);
  k_bucket<<<NBK, 256, 0, stream>>>(stage, bucketBase, edges, row_off, la);

  // ---- layer 0 aggregation: xl -> h0(regionB) ----
  k_agg<<<eblocks16, 256, 0, stream>>>(row_off, edges, asrcA, adstA, la,
                                       cvals + 0, xl, b0c, regionB, NN);
  // ---- layer 1 ----
  k_gemm<false><<<gblocks, 256, 0, stream>>>(regionB, WT1, as1c, ad1c,
                                             xl, asrcA, adstA, nullptr, nullptr, NN);
  k_agg<<<eblocks16, 256, 0, stream>>>(row_off, edges, asrcA, adstA, la,
                                       cvals + 1, xl, b1c, regionA, NN);
  // ---- heads ----
  k_gemm<true><<<gblocks, 256, 0, stream>>>(regionA, WTh, hvs, hvd,
                                            xl, nullptr, adstA, asAB, adstB, NN);
  k_aggh<<<eblocks16, 256, 0, stream>>>(row_off, edges, asAB, adstA, adstB,
                                        la, cvals + 2, xl, bh, outf, NN);
}